// Round 1
// baseline (1695.738 us; speedup 1.0000x reference)
//
#include <hip/hip_runtime.h>
#include <hip/hip_bf16.h>
#include <cstdint>
#include <cstddef>

typedef __bf16 bf16;
typedef __attribute__((ext_vector_type(8))) __bf16 bf16x8;
typedef __attribute__((ext_vector_type(4))) float f32x4;

constexpr int B_ = 4, QN = 1024, MCTX = 3072, D_ = 512, H_ = 8, DHE = 64, L_ = 6, FF_ = 2048;
constexpr float SCALE_ = 0.125f;  // 64^-0.5

__device__ __forceinline__ f32x4 mfma16(bf16x8 a, bf16x8 b, f32x4 c) {
  return __builtin_amdgcn_mfma_f32_16x16x32_bf16(a, b, c, 0, 0, 0);
}

__device__ __forceinline__ void gl_lds16(const bf16* g, bf16* l) {
  __builtin_amdgcn_global_load_lds((const __attribute__((address_space(1))) void*)g,
                                   (__attribute__((address_space(3))) void*)l, 16, 0, 0);
}

// ---------------- LayerNorm: fp32 in -> bf16 out, one wave per row (D=512) ----
__global__ __launch_bounds__(256) void ln_kernel(const float* __restrict__ x,
                                                 const float* __restrict__ g,
                                                 const float* __restrict__ b,
                                                 bf16* __restrict__ out, int rows) {
  int wid = threadIdx.x >> 6, lane = threadIdx.x & 63;
  int row = blockIdx.x * 4 + wid;
  if (row >= rows) return;
  const float* xr = x + (size_t)row * D_;
  f32x4 a0 = *(const f32x4*)(xr + lane * 8);
  f32x4 a1 = *(const f32x4*)(xr + lane * 8 + 4);
  float s = 0.f;
#pragma unroll
  for (int i = 0; i < 4; i++) { s += a0[i]; s += a1[i]; }
#pragma unroll
  for (int d = 1; d < 64; d <<= 1) s += __shfl_xor(s, d);
  float mean = s * (1.0f / 512.0f);
  float q = 0.f;
#pragma unroll
  for (int i = 0; i < 4; i++) {
    float t0 = a0[i] - mean, t1 = a1[i] - mean;
    q += t0 * t0 + t1 * t1;
  }
#pragma unroll
  for (int d = 1; d < 64; d <<= 1) q += __shfl_xor(q, d);
  float rstd = rsqrtf(q * (1.0f / 512.0f) + 1e-5f);
  f32x4 g0 = *(const f32x4*)(g + lane * 8);
  f32x4 g1 = *(const f32x4*)(g + lane * 8 + 4);
  f32x4 b0 = *(const f32x4*)(b + lane * 8);
  f32x4 b1 = *(const f32x4*)(b + lane * 8 + 4);
  bf16x8 o;
#pragma unroll
  for (int i = 0; i < 4; i++) {
    o[i] = (bf16)((a0[i] - mean) * rstd * g0[i] + b0[i]);
    o[i + 4] = (bf16)((a1[i] - mean) * rstd * g1[i] + b1[i]);
  }
  *(bf16x8*)(out + (size_t)row * D_ + lane * 8) = o;
}

// ------------- weight transpose fp32 [K][N] -> bf16 [N][K], 64x64 LDS tiles ---
__global__ __launch_bounds__(256) void wtrans_kernel(const float* __restrict__ w,
                                                     bf16* __restrict__ wt, int K, int N) {
  __shared__ float tile[64][65];
  int tx = threadIdx.x, ty = threadIdx.y;
  int n0 = blockIdx.x * 64, k0 = blockIdx.y * 64;
#pragma unroll
  for (int p = 0; p < 16; p++)
    tile[p * 4 + ty][tx] = w[(size_t)(k0 + p * 4 + ty) * N + n0 + tx];
  __syncthreads();
#pragma unroll
  for (int p = 0; p < 16; p++)
    wt[(size_t)(n0 + p * 4 + ty) * K + k0 + tx] = (bf16)tile[tx][p * 4 + ty];
}

// ------------- V repack: [b,s,stride] (col off) -> VT [b,h,dh,Skv], bf16 ------
__global__ __launch_bounds__(256) void vtrans_kernel(const bf16* __restrict__ src,
                                                     bf16* __restrict__ vt,
                                                     int Skv, int rstride, int coloff) {
  __shared__ bf16 tile[64][65];
  int tx = threadIdx.x, ty = threadIdx.y;
  int s0 = blockIdx.x * 64, h = blockIdx.y, b = blockIdx.z;
  const bf16* sp = src + (size_t)b * Skv * rstride + coloff + h * 64;
#pragma unroll
  for (int p = 0; p < 16; p++)
    tile[p * 4 + ty][tx] = sp[(size_t)(s0 + p * 4 + ty) * rstride + tx];
  __syncthreads();
  bf16* op = vt + ((size_t)(b * H_ + h) * 64) * Skv;
#pragma unroll
  for (int p = 0; p < 16; p++)
    op[(size_t)(p * 4 + ty) * Skv + s0 + tx] = tile[tx][p * 4 + ty];
}

// ------------- GEMM: A[M][K] bf16 x BT[N][K] bf16 -> C, m97-style ------------
// EPI 0: bf16 out (with output-row remap); EPI 1: GELU -> bf16; EPI 2: +bias? +resid -> f32
template <int EPI>
__global__ __launch_bounds__(256) void gemm_bt(const bf16* __restrict__ A,
                                               const bf16* __restrict__ BT,
                                               void* __restrict__ Cout,
                                               const float* __restrict__ resid,
                                               const float* __restrict__ bias,
                                               int M, int N, int K,
                                               int rpbi, int rpbo, int roff) {
  __shared__ bf16 smA[128 * 32];
  __shared__ bf16 smB[128 * 32];
  const int tid = threadIdx.x, wid = tid >> 6, lane = tid & 63;
  const int lr = lane & 15, lg = lane >> 4;
  const int tm = blockIdx.y * 128, tn = blockIdx.x * 128;
  const int wr = (wid >> 1) * 64, wc = (wid & 1) * 64;
  const int c0 = wid * 2;
  const int srow = lane >> 2, scol = (lane & 3) * 8;

  const bf16* gA0 = A + (size_t)(tm + c0 * 16 + srow) * K + scol;
  const bf16* gA1 = gA0 + (size_t)16 * K;
  const bf16* gB0 = BT + (size_t)(tn + c0 * 16 + srow) * K + scol;
  const bf16* gB1 = gB0 + (size_t)16 * K;
  bf16* lA0 = smA + c0 * 512;
  bf16* lA1 = lA0 + 512;
  bf16* lB0 = smB + c0 * 512;
  bf16* lB1 = lB0 + 512;

  f32x4 acc[4][4] = {};

  for (int kt = 0; kt < K; kt += 32) {
    gl_lds16(gA0 + kt, lA0);
    gl_lds16(gA1 + kt, lA1);
    gl_lds16(gB0 + kt, lB0);
    gl_lds16(gB1 + kt, lB1);
    __syncthreads();
    bf16x8 af[4], bfv[4];
#pragma unroll
    for (int i = 0; i < 4; i++)
      af[i] = *(const bf16x8*)(smA + (wr + i * 16 + lr) * 32 + lg * 8);
#pragma unroll
    for (int j = 0; j < 4; j++)
      bfv[j] = *(const bf16x8*)(smB + (wc + j * 16 + lr) * 32 + lg * 8);
#pragma unroll
    for (int i = 0; i < 4; i++)
#pragma unroll
      for (int j = 0; j < 4; j++)
        acc[i][j] = mfma16(af[i], bfv[j], acc[i][j]);
    __syncthreads();
  }

#pragma unroll
  for (int i = 0; i < 4; i++) {
#pragma unroll
    for (int r = 0; r < 4; r++) {
      int row = tm + wr + i * 16 + lg * 4 + r;
      int orow = (row / rpbi) * rpbo + (row % rpbi) + roff;
#pragma unroll
      for (int j = 0; j < 4; j++) {
        int col = tn + wc + j * 16 + lr;
        float v = acc[i][j][r];
        if (EPI == 0) {
          ((bf16*)Cout)[(size_t)orow * N + col] = (bf16)v;
        } else if (EPI == 1) {
          float gv = 0.5f * v * (1.0f + erff(v * 0.70710678118f));
          ((bf16*)Cout)[(size_t)orow * N + col] = (bf16)gv;
        } else {
          if (bias) v += bias[col];
          v += resid[(size_t)orow * N + col];
          ((float*)Cout)[(size_t)orow * N + col] = v;
        }
      }
    }
  }
}

// ------------- flash attention: 4 waves/block, 16 q-rows/wave, 32-key tiles ---
// q: [b*QN][qstride] col h*64; k: [b*Skv][kstride] col h*64; vt: [b,h,64,Skv]
// out: [b*QN][512] bf16. mask: key j allowed iff j <= Moff + q_global.
__global__ __launch_bounds__(256) void attn_kernel(const bf16* __restrict__ q, int qstride,
                                                   const bf16* __restrict__ k, int kstride,
                                                   const bf16* __restrict__ vt,
                                                   bf16* __restrict__ out,
                                                   int Skv, int Moff) {
  __shared__ bf16 plds[4][16][32];
  const int wid = threadIdx.x >> 6, lane = threadIdx.x & 63;
  const int lr = lane & 15, lg = lane >> 4;
  const int b = blockIdx.z, h = blockIdx.y;
  const int q0 = blockIdx.x * 64 + wid * 16;

  const bf16* qp = q + (size_t)(b * QN + q0 + lr) * qstride + h * DHE;
  bf16x8 qa0 = *(const bf16x8*)(qp + lg * 8);
  bf16x8 qa1 = *(const bf16x8*)(qp + 32 + lg * 8);

  f32x4 o[4] = {};
  float m[4] = {-3e38f, -3e38f, -3e38f, -3e38f};
  float l[4] = {0.f, 0.f, 0.f, 0.f};

  int jhi = Moff + q0 + 15;
  if (jhi > Skv - 1) jhi = Skv - 1;
  const int ntiles = jhi / 32 + 1;

  for (int kt = 0; kt < ntiles; kt++) {
    const int j0 = kt * 32;
    f32x4 s0v = {0.f, 0.f, 0.f, 0.f}, s1v = {0.f, 0.f, 0.f, 0.f};
    {
      const bf16* kp0 = k + (size_t)(b * Skv + j0 + lr) * kstride + h * DHE;
      const bf16* kp1 = kp0 + (size_t)16 * kstride;
      bf16x8 kb;
      kb = *(const bf16x8*)(kp0 + lg * 8);
      s0v = mfma16(qa0, kb, s0v);
      kb = *(const bf16x8*)(kp0 + 32 + lg * 8);
      s0v = mfma16(qa1, kb, s0v);
      kb = *(const bf16x8*)(kp1 + lg * 8);
      s1v = mfma16(qa0, kb, s1v);
      kb = *(const bf16x8*)(kp1 + 32 + lg * 8);
      s1v = mfma16(qa1, kb, s1v);
    }
    float pm[4];
#pragma unroll
    for (int r = 0; r < 4; r++) {
      int lim = Moff + q0 + lg * 4 + r;
      float x0 = s0v[r] * SCALE_;
      float x1 = s1v[r] * SCALE_;
      if (j0 + lr > lim) x0 = -3e38f;
      if (j0 + 16 + lr > lim) x1 = -3e38f;
      s0v[r] = x0; s1v[r] = x1;
      pm[r] = fmaxf(x0, x1);
    }
#pragma unroll
    for (int d = 1; d < 16; d <<= 1) {
#pragma unroll
      for (int r = 0; r < 4; r++) pm[r] = fmaxf(pm[r], __shfl_xor(pm[r], d));
    }
#pragma unroll
    for (int r = 0; r < 4; r++) {
      float mn = fmaxf(m[r], pm[r]);
      float sc = __expf(m[r] - mn);
      m[r] = mn;
      float p0 = __expf(s0v[r] - mn);
      float p1 = __expf(s1v[r] - mn);
      s0v[r] = p0; s1v[r] = p1;
      float rs = p0 + p1;
#pragma unroll
      for (int d = 1; d < 16; d <<= 1) rs += __shfl_xor(rs, d);
      l[r] = l[r] * sc + rs;
      o[0][r] *= sc; o[1][r] *= sc; o[2][r] *= sc; o[3][r] *= sc;
    }
    // reshape P (D-layout) -> A-fragment layout through per-wave LDS
#pragma unroll
    for (int r = 0; r < 4; r++) {
      plds[wid][lg * 4 + r][lr] = (bf16)s0v[r];
      plds[wid][lg * 4 + r][16 + lr] = (bf16)s1v[r];
    }
    bf16x8 pa = *(const bf16x8*)&plds[wid][lr][lg * 8];
#pragma unroll
    for (int f = 0; f < 4; f++) {
      const bf16* vp = vt + ((size_t)((b * H_ + h) * DHE + f * 16 + lr)) * Skv + j0 + lg * 8;
      bf16x8 vb = *(const bf16x8*)vp;
      o[f] = mfma16(pa, vb, o[f]);
    }
  }
#pragma unroll
  for (int f = 0; f < 4; f++) {
#pragma unroll
    for (int r = 0; r < 4; r++) {
      out[(size_t)(b * QN + q0 + lg * 4 + r) * D_ + h * DHE + f * 16 + lr] =
          (bf16)(o[f][r] / l[r]);
    }
  }
}

// -----------------------------------------------------------------------------
static void launch_gemm(hipStream_t st, int epi, const bf16* A, const bf16* BT, void* C,
                        const float* res, const float* bias,
                        int M, int N, int K, int rpbi, int rpbo, int roff) {
  dim3 grid(N / 128, M / 128), blk(256, 1, 1);
  switch (epi) {
    case 0:
      hipLaunchKernelGGL(HIP_KERNEL_NAME(gemm_bt<0>), grid, blk, 0, st, A, BT, C, res, bias, M, N, K, rpbi, rpbo, roff);
      break;
    case 1:
      hipLaunchKernelGGL(HIP_KERNEL_NAME(gemm_bt<1>), grid, blk, 0, st, A, BT, C, res, bias, M, N, K, rpbi, rpbo, roff);
      break;
    default:
      hipLaunchKernelGGL(HIP_KERNEL_NAME(gemm_bt<2>), grid, blk, 0, st, A, BT, C, res, bias, M, N, K, rpbi, rpbo, roff);
      break;
  }
}

extern "C" void kernel_launch(void* const* d_in, const int* in_sizes, int n_in,
                              void* d_out, int out_size, void* d_ws, size_t ws_size,
                              hipStream_t stream) {
  const float* x       = (const float*)d_in[0];
  const float* ctx     = (const float*)d_in[1];
  const float* pa_ng   = (const float*)d_in[2];
  const float* pa_nb   = (const float*)d_in[3];
  const float* pa_cg   = (const float*)d_in[4];
  const float* pa_cb   = (const float*)d_in[5];
  const float* pa_wq   = (const float*)d_in[6];
  const float* pa_wkv  = (const float*)d_in[7];
  const float* pa_wo   = (const float*)d_in[8];
  const float* pa_wob  = (const float*)d_in[9];
  const float* pf_g    = (const float*)d_in[10];
  const float* pf_b    = (const float*)d_in[11];
  const float* pf_w1   = (const float*)d_in[12];
  const float* pf_w2   = (const float*)d_in[13];
  const float* sa_g    = (const float*)d_in[14];
  const float* sa_b    = (const float*)d_in[15];
  const float* sa_wqkv = (const float*)d_in[16];
  const float* sa_wo   = (const float*)d_in[17];
  const float* sf_g    = (const float*)d_in[18];
  const float* sf_b    = (const float*)d_in[19];
  const float* sf_w1   = (const float*)d_in[20];
  const float* sf_w2   = (const float*)d_in[21];
  float* xo = (float*)d_out;

  char* ws = (char*)d_ws;
  size_t off = 0;
  auto alloc = [&](size_t bytes) -> char* {
    char* p = ws + off;
    off += (bytes + 255) & ~(size_t)255;
    return p;
  };

  // bf16 transposed weights
  bf16* wqT    = (bf16*)alloc((size_t)512 * 512 * 2);
  bf16* wkvT   = (bf16*)alloc((size_t)1024 * 512 * 2);
  bf16* woT    = (bf16*)alloc((size_t)512 * 512 * 2);
  bf16* w1T    = (bf16*)alloc((size_t)2048 * 512 * 2);
  bf16* w2T    = (bf16*)alloc((size_t)512 * 2048 * 2);
  bf16* saqkvT = (bf16*)alloc((size_t)L_ * 1536 * 512 * 2);
  bf16* sawoT  = (bf16*)alloc((size_t)L_ * 512 * 512 * 2);
  bf16* sfw1T  = (bf16*)alloc((size_t)L_ * 2048 * 512 * 2);
  bf16* sfw2T  = (bf16*)alloc((size_t)L_ * 512 * 2048 * 2);
  // activations
  bf16* xn    = (bf16*)alloc((size_t)4096 * 512 * 2);
  bf16* reg1  = (bf16*)alloc((size_t)12288 * 512 * 2);       // cn (prefix) / qkv (layers)
  bf16* qb    = (bf16*)alloc((size_t)4096 * 512 * 2);
  bf16* reg2  = (bf16*)alloc((size_t)B_ * 4096 * 1024 * 2);  // kv (prefix) / ffh (later)
  bf16* vtb   = (bf16*)alloc((size_t)B_ * H_ * 64 * 4096 * 2);
  bf16* attnb = (bf16*)alloc((size_t)4096 * 512 * 2);
  bf16* cn = reg1;
  bf16* qkvb = reg1;
  bf16* kvb = reg2;
  bf16* ffh = reg2;
  (void)ws_size; (void)in_sizes; (void)n_in; (void)out_size;

  dim3 b64(64, 4, 1);
  // ---- weight prep ----
  wtrans_kernel<<<dim3(8, 8), b64, 0, stream>>>(pa_wq, wqT, 512, 512);
  wtrans_kernel<<<dim3(16, 8), b64, 0, stream>>>(pa_wkv, wkvT, 512, 1024);
  wtrans_kernel<<<dim3(8, 8), b64, 0, stream>>>(pa_wo, woT, 512, 512);
  wtrans_kernel<<<dim3(32, 8), b64, 0, stream>>>(pf_w1, w1T, 512, 2048);
  wtrans_kernel<<<dim3(8, 32), b64, 0, stream>>>(pf_w2, w2T, 2048, 512);
  for (int l = 0; l < L_; l++) {
    wtrans_kernel<<<dim3(24, 8), b64, 0, stream>>>(sa_wqkv + (size_t)l * 512 * 1536,
                                                   saqkvT + (size_t)l * 1536 * 512, 512, 1536);
    wtrans_kernel<<<dim3(8, 8), b64, 0, stream>>>(sa_wo + (size_t)l * 512 * 512,
                                                  sawoT + (size_t)l * 512 * 512, 512, 512);
    wtrans_kernel<<<dim3(32, 8), b64, 0, stream>>>(sf_w1 + (size_t)l * 512 * 2048,
                                                   sfw1T + (size_t)l * 2048 * 512, 512, 2048);
    wtrans_kernel<<<dim3(8, 32), b64, 0, stream>>>(sf_w2 + (size_t)l * 2048 * 512,
                                                   sfw2T + (size_t)l * 512 * 2048, 2048, 512);
  }

  // ---- prefix attention block ----
  ln_kernel<<<1024, 256, 0, stream>>>(x, pa_ng, pa_nb, xn, 4096);
  ln_kernel<<<3072, 256, 0, stream>>>(ctx, pa_cg, pa_cb, cn, 12288);
  launch_gemm(stream, 0, xn, wqT, qb, nullptr, nullptr, 4096, 512, 512, 4096, 4096, 0);
  launch_gemm(stream, 0, cn, wkvT, kvb, nullptr, nullptr, 12288, 1024, 512, 3072, 4096, 0);
  launch_gemm(stream, 0, xn, wkvT, kvb, nullptr, nullptr, 4096, 1024, 512, 1024, 4096, 3072);
  vtrans_kernel<<<dim3(64, H_, B_), b64, 0, stream>>>(kvb, vtb, 4096, 1024, 512);
  attn_kernel<<<dim3(QN / 64, H_, B_), 256, 0, stream>>>(qb, 512, kvb, 1024, vtb, attnb, 4096, MCTX);
  launch_gemm(stream, 2, attnb, woT, xo, x, pa_wob, 4096, 512, 512, 4096, 4096, 0);
  // prefix FF
  ln_kernel<<<1024, 256, 0, stream>>>(xo, pf_g, pf_b, xn, 4096);
  launch_gemm(stream, 1, xn, w1T, ffh, nullptr, nullptr, 4096, 2048, 512, 4096, 4096, 0);
  launch_gemm(stream, 2, ffh, w2T, xo, xo, nullptr, 4096, 512, 2048, 4096, 4096, 0);

  // ---- depth x (self-attn + FF) ----
  for (int l = 0; l < L_; l++) {
    ln_kernel<<<1024, 256, 0, stream>>>(xo, sa_g + l * 512, sa_b + l * 512, xn, 4096);
    launch_gemm(stream, 0, xn, saqkvT + (size_t)l * 1536 * 512, qkvb, nullptr, nullptr,
                4096, 1536, 512, 4096, 4096, 0);
    vtrans_kernel<<<dim3(16, H_, B_), b64, 0, stream>>>(qkvb, vtb, 1024, 1536, 1024);
    attn_kernel<<<dim3(QN / 64, H_, B_), 256, 0, stream>>>(qkvb, 1536, qkvb + 512, 1536,
                                                           vtb, attnb, 1024, 0);
    launch_gemm(stream, 2, attnb, sawoT + (size_t)l * 512 * 512, xo, xo, nullptr,
                4096, 512, 512, 4096, 4096, 0);
    ln_kernel<<<1024, 256, 0, stream>>>(xo, sf_g + l * 512, sf_b + l * 512, xn, 4096);
    launch_gemm(stream, 1, xn, sfw1T + (size_t)l * 2048 * 512, ffh, nullptr, nullptr,
                4096, 2048, 512, 4096, 4096, 0);
    launch_gemm(stream, 2, ffh, sfw2T + (size_t)l * 512 * 2048, xo, xo, nullptr,
                4096, 512, 2048, 4096, 4096, 0);
  }
}

// Round 2
// 1377.517 us; speedup vs baseline: 1.2310x; 1.2310x over previous
//
#include <hip/hip_runtime.h>
#include <hip/hip_bf16.h>
#include <cstdint>
#include <cstddef>

typedef __bf16 bf16;
typedef __attribute__((ext_vector_type(8))) __bf16 bf16x8;
typedef __attribute__((ext_vector_type(4))) __bf16 bf16x4;
typedef __attribute__((ext_vector_type(4))) float f32x4;

constexpr int B_ = 4, QN = 1024, MCTX = 3072, D_ = 512, H_ = 8, DHE = 64, L_ = 6, FF_ = 2048;
constexpr float SCALE_ = 0.125f;  // 64^-0.5

__device__ __forceinline__ f32x4 mfma16(bf16x8 a, bf16x8 b, f32x4 c) {
  return __builtin_amdgcn_mfma_f32_16x16x32_bf16(a, b, c, 0, 0, 0);
}

__device__ __forceinline__ void gl_lds16(const bf16* g, bf16* l) {
  __builtin_amdgcn_global_load_lds((const __attribute__((address_space(1))) void*)g,
                                   (__attribute__((address_space(3))) void*)l, 16, 0, 0);
}

// ---------------- LayerNorm: fp32 in -> bf16 out, one wave per row (D=512) ----
__global__ __launch_bounds__(256) void ln_kernel(const float* __restrict__ x,
                                                 const float* __restrict__ g,
                                                 const float* __restrict__ b,
                                                 bf16* __restrict__ out, int rows) {
  int wid = threadIdx.x >> 6, lane = threadIdx.x & 63;
  int row = blockIdx.x * 4 + wid;
  if (row >= rows) return;
  const float* xr = x + (size_t)row * D_;
  f32x4 a0 = *(const f32x4*)(xr + lane * 8);
  f32x4 a1 = *(const f32x4*)(xr + lane * 8 + 4);
  float s = 0.f;
#pragma unroll
  for (int i = 0; i < 4; i++) { s += a0[i]; s += a1[i]; }
#pragma unroll
  for (int d = 1; d < 64; d <<= 1) s += __shfl_xor(s, d);
  float mean = s * (1.0f / 512.0f);
  float q = 0.f;
#pragma unroll
  for (int i = 0; i < 4; i++) {
    float t0 = a0[i] - mean, t1 = a1[i] - mean;
    q += t0 * t0 + t1 * t1;
  }
#pragma unroll
  for (int d = 1; d < 64; d <<= 1) q += __shfl_xor(q, d);
  float rstd = rsqrtf(q * (1.0f / 512.0f) + 1e-5f);
  f32x4 g0 = *(const f32x4*)(g + lane * 8);
  f32x4 g1 = *(const f32x4*)(g + lane * 8 + 4);
  f32x4 b0 = *(const f32x4*)(b + lane * 8);
  f32x4 b1 = *(const f32x4*)(b + lane * 8 + 4);
  bf16x8 o;
#pragma unroll
  for (int i = 0; i < 4; i++) {
    o[i] = (bf16)((a0[i] - mean) * rstd * g0[i] + b0[i]);
    o[i + 4] = (bf16)((a1[i] - mean) * rstd * g1[i] + b1[i]);
  }
  *(bf16x8*)(out + (size_t)row * D_ + lane * 8) = o;
}

// ------------- weight transpose fp32 [K][N] -> bf16 [N][K], 64x64 LDS tiles ---
__global__ __launch_bounds__(256) void wtrans_kernel(const float* __restrict__ w,
                                                     bf16* __restrict__ wt, int K, int N) {
  __shared__ float tile[64][65];
  int tx = threadIdx.x, ty = threadIdx.y;
  int n0 = blockIdx.x * 64, k0 = blockIdx.y * 64;
#pragma unroll
  for (int p = 0; p < 16; p++)
    tile[p * 4 + ty][tx] = w[(size_t)(k0 + p * 4 + ty) * N + n0 + tx];
  __syncthreads();
#pragma unroll
  for (int p = 0; p < 16; p++)
    wt[(size_t)(n0 + p * 4 + ty) * K + k0 + tx] = (bf16)tile[tx][p * 4 + ty];
}

// ------------- V repack: [b,s,stride] (col off) -> VT [b,h,dh,Skv], bf16 ------
__global__ __launch_bounds__(256) void vtrans_kernel(const bf16* __restrict__ src,
                                                     bf16* __restrict__ vt,
                                                     int Skv, int rstride, int coloff) {
  __shared__ bf16 tile[64][65];
  int tx = threadIdx.x, ty = threadIdx.y;
  int s0 = blockIdx.x * 64, h = blockIdx.y, b = blockIdx.z;
  const bf16* sp = src + (size_t)b * Skv * rstride + coloff + h * 64;
#pragma unroll
  for (int p = 0; p < 16; p++)
    tile[p * 4 + ty][tx] = sp[(size_t)(s0 + p * 4 + ty) * rstride + tx];
  __syncthreads();
  bf16* op = vt + ((size_t)(b * H_ + h) * 64) * Skv;
#pragma unroll
  for (int p = 0; p < 16; p++)
    op[(size_t)(p * 4 + ty) * Skv + s0 + tx] = tile[tx][p * 4 + ty];
}

// ------------- GEMM: A[M][K] bf16 x BT[N][K] bf16 -> C, m97-style ------------
template <int EPI>
__global__ __launch_bounds__(256) void gemm_bt(const bf16* __restrict__ A,
                                               const bf16* __restrict__ BT,
                                               void* __restrict__ Cout,
                                               const float* __restrict__ resid,
                                               const float* __restrict__ bias,
                                               int M, int N, int K,
                                               int rpbi, int rpbo, int roff) {
  __shared__ bf16 smA[128 * 32];
  __shared__ bf16 smB[128 * 32];
  const int tid = threadIdx.x, wid = tid >> 6, lane = tid & 63;
  const int lr = lane & 15, lg = lane >> 4;
  const int tm = blockIdx.y * 128, tn = blockIdx.x * 128;
  const int wr = (wid >> 1) * 64, wc = (wid & 1) * 64;
  const int c0 = wid * 2;
  const int srow = lane >> 2, scol = (lane & 3) * 8;

  const bf16* gA0 = A + (size_t)(tm + c0 * 16 + srow) * K + scol;
  const bf16* gA1 = gA0 + (size_t)16 * K;
  const bf16* gB0 = BT + (size_t)(tn + c0 * 16 + srow) * K + scol;
  const bf16* gB1 = gB0 + (size_t)16 * K;
  bf16* lA0 = smA + c0 * 512;
  bf16* lA1 = lA0 + 512;
  bf16* lB0 = smB + c0 * 512;
  bf16* lB1 = lB0 + 512;

  f32x4 acc[4][4] = {};

  for (int kt = 0; kt < K; kt += 32) {
    gl_lds16(gA0 + kt, lA0);
    gl_lds16(gA1 + kt, lA1);
    gl_lds16(gB0 + kt, lB0);
    gl_lds16(gB1 + kt, lB1);
    __syncthreads();
    bf16x8 af[4], bfv[4];
#pragma unroll
    for (int i = 0; i < 4; i++)
      af[i] = *(const bf16x8*)(smA + (wr + i * 16 + lr) * 32 + lg * 8);
#pragma unroll
    for (int j = 0; j < 4; j++)
      bfv[j] = *(const bf16x8*)(smB + (wc + j * 16 + lr) * 32 + lg * 8);
#pragma unroll
    for (int i = 0; i < 4; i++)
#pragma unroll
      for (int j = 0; j < 4; j++)
        acc[i][j] = mfma16(af[i], bfv[j], acc[i][j]);
    __syncthreads();
  }

#pragma unroll
  for (int i = 0; i < 4; i++) {
#pragma unroll
    for (int r = 0; r < 4; r++) {
      int row = tm + wr + i * 16 + lg * 4 + r;
      int orow = (row / rpbi) * rpbo + (row % rpbi) + roff;
#pragma unroll
      for (int j = 0; j < 4; j++) {
        int col = tn + wc + j * 16 + lr;
        float v = acc[i][j][r];
        if (EPI == 0) {
          ((bf16*)Cout)[(size_t)orow * N + col] = (bf16)v;
        } else if (EPI == 1) {
          float gv = 0.5f * v * (1.0f + erff(v * 0.70710678118f));
          ((bf16*)Cout)[(size_t)orow * N + col] = (bf16)gv;
        } else {
          if (bias) v += bias[col];
          v += resid[(size_t)orow * N + col];
          ((float*)Cout)[(size_t)orow * N + col] = v;
        }
      }
    }
  }
}

// ------------- flash attention v2: swapped QK^T, 64-key LDS-staged tiles ------
// q: [b*QN][qstride] col h*64; k: [b*Skv][kstride] col h*64; vt: [b,h,64,Skv]
// out: [b*QN][512] bf16. key j allowed iff j <= Moff + q_global.
__global__ __launch_bounds__(256) void attn_kernel(const bf16* __restrict__ q, int qstride,
                                                   const bf16* __restrict__ k, int kstride,
                                                   const bf16* __restrict__ vt,
                                                   bf16* __restrict__ out,
                                                   int Skv, int Moff) {
  // fragment-order LDS tiles: chunk c (16B) holds, for lane fl=c&63 of frag (c>>6):
  // K: row (c>>7)*16 + (fl&15), dh elems ((c>>6)&1)*32 + (fl>>4)*8
  // VT: dh  (c>>7)*16 + (fl&15), key elems ((c>>6)&1)*32 + (fl>>4)*8
  __shared__ bf16 kls[2][4096];
  __shared__ bf16 vls[2][4096];
  __shared__ bf16 pls[4][1024];

  const int tid = threadIdx.x, wid = tid >> 6, lane = tid & 63;
  const int lr = lane & 15, lg = lane >> 4, lg4 = lg * 4;
  const int b = blockIdx.z, h = blockIdx.y;
  const int q0b = blockIdx.x * 64;
  const int q0w = q0b + wid * 16;

  // staging roles (chunk c = round*256 + tid)
  const int ss = (tid >> 6) & 1;
  const int sel = ss * 32 + ((tid >> 4) & 3) * 8;
  const int srow0 = (tid >> 7) * 16 + (tid & 15);
  const bf16* kbase = k + (size_t)b * Skv * kstride + h * DHE + sel;
  const bf16* vbase = vt + (size_t)((b * H_ + h) * DHE) * Skv + sel;

  // Q B-frags, pre-scaled (x0.125 exact in bf16)
  const bf16* qp = q + (size_t)(b * QN + q0w + lr) * qstride + h * DHE;
  bf16x8 qa0 = *(const bf16x8*)(qp + lg * 8);
  bf16x8 qa1 = *(const bf16x8*)(qp + 32 + lg * 8);
#pragma unroll
  for (int i = 0; i < 8; i++) {
    qa0[i] = (bf16)((float)qa0[i] * SCALE_);
    qa1[i] = (bf16)((float)qa1[i] * SCALE_);
  }

  f32x4 o[4] = {};
  float mr = -3e38f, lrun = 0.f;

  int jmaxb = Moff + q0b + 63;
  if (jmaxb > Skv - 1) jmaxb = Skv - 1;
  const int nt = jmaxb / 64 + 1;

  auto stage = [&](int bi, int j0) {
    gl_lds16(kbase + (size_t)(j0 + srow0) * kstride, &kls[bi][wid * 512]);
    gl_lds16(kbase + (size_t)(j0 + srow0 + 32) * kstride, &kls[bi][2048 + wid * 512]);
    gl_lds16(vbase + (size_t)srow0 * Skv + j0, &vls[bi][wid * 512]);
    gl_lds16(vbase + (size_t)(srow0 + 32) * Skv + j0, &vls[bi][2048 + wid * 512]);
  };

  stage(0, 0);
  __syncthreads();
  int buf = 0;
  bf16* pw = &pls[wid][0];

  for (int t = 0; t < nt; ++t) {
    if (t + 1 < nt) stage(buf ^ 1, (t + 1) * 64);
    const int j0 = t * 64;
    const bf16* kbp = &kls[buf][0];
    const bf16* vbp = &vls[buf][0];

    // QK^T swapped: rows=keys, cols=q. lane holds q=lr, keys kg*16+lg4+r
    f32x4 sv[4];
#pragma unroll
    for (int kg = 0; kg < 4; kg++) {
      bf16x8 k0 = *(const bf16x8*)(kbp + (kg * 128 + lane) * 8);
      bf16x8 k1 = *(const bf16x8*)(kbp + (kg * 128 + 64 + lane) * 8);
      f32x4 z = {0.f, 0.f, 0.f, 0.f};
      z = mfma16(k0, qa0, z);
      z = mfma16(k1, qa1, z);
      sv[kg] = z;
    }
    const bool full = (j0 + 63 <= Moff + q0w);
    if (!full) {
      const int limq = Moff + q0w + lr;
#pragma unroll
      for (int kg = 0; kg < 4; kg++)
#pragma unroll
        for (int r = 0; r < 4; r++)
          if (j0 + kg * 16 + lg4 + r > limq) sv[kg][r] = -3e38f;
    }
    float pmax = sv[0][0];
#pragma unroll
    for (int kg = 0; kg < 4; kg++)
#pragma unroll
      for (int r = 0; r < 4; r++) pmax = fmaxf(pmax, sv[kg][r]);
    pmax = fmaxf(pmax, __shfl_xor(pmax, 16));
    pmax = fmaxf(pmax, __shfl_xor(pmax, 32));
    if (__any(pmax > mr + 8.f)) {  // defer-max: rescale only on real growth
      float mn = fmaxf(mr, pmax);
      float scl = __expf(mr - mn);
      mr = mn;
      lrun *= scl;
      float c0 = __shfl(scl, lg4 + 0), c1 = __shfl(scl, lg4 + 1);
      float c2 = __shfl(scl, lg4 + 2), c3 = __shfl(scl, lg4 + 3);
#pragma unroll
      for (int f = 0; f < 4; f++) {
        o[f][0] *= c0; o[f][1] *= c1; o[f][2] *= c2; o[f][3] *= c3;
      }
    }
    float rsum = 0.f;
#pragma unroll
    for (int kg = 0; kg < 4; kg++) {
      float p0 = __expf(sv[kg][0] - mr);
      float p1 = __expf(sv[kg][1] - mr);
      float p2 = __expf(sv[kg][2] - mr);
      float p3 = __expf(sv[kg][3] - mr);
      rsum += (p0 + p1) + (p2 + p3);
      bf16x4 pk = {(bf16)p0, (bf16)p1, (bf16)p2, (bf16)p3};
      const int k8 = kg * 2 + (lg >> 1);
      *(bf16x4*)(pw + ((k8 >> 2) * 64 + (k8 & 3) * 16 + lr) * 8 + (lg & 1) * 4) = pk;
    }
    rsum += __shfl_xor(rsum, 16);
    rsum += __shfl_xor(rsum, 32);
    lrun += rsum;
    // PV: A = P (rows q, k=keys), B = VT rows (dh)
    bf16x8 pa0 = *(const bf16x8*)(pw + lane * 8);
    bf16x8 pa1 = *(const bf16x8*)(pw + (64 + lane) * 8);
#pragma unroll
    for (int f = 0; f < 4; f++) {
      bf16x8 v0 = *(const bf16x8*)(vbp + (f * 128 + lane) * 8);
      bf16x8 v1 = *(const bf16x8*)(vbp + (f * 128 + 64 + lane) * 8);
      o[f] = mfma16(pa0, v0, o[f]);
      o[f] = mfma16(pa1, v1, o[f]);
    }
    __syncthreads();
    buf ^= 1;
  }

  float linv = 1.0f / lrun;
  float li[4];
#pragma unroll
  for (int r = 0; r < 4; r++) li[r] = __shfl(linv, lg4 + r);
#pragma unroll
  for (int f = 0; f < 4; f++)
#pragma unroll
    for (int r = 0; r < 4; r++)
      out[(size_t)(b * QN + q0w + lg4 + r) * D_ + h * DHE + f * 16 + lr] =
          (bf16)(o[f][r] * li[r]);
}

// -----------------------------------------------------------------------------
static void launch_gemm(hipStream_t st, int epi, const bf16* A, const bf16* BT, void* C,
                        const float* res, const float* bias,
                        int M, int N, int K, int rpbi, int rpbo, int roff) {
  dim3 grid(N / 128, M / 128), blk(256, 1, 1);
  switch (epi) {
    case 0:
      hipLaunchKernelGGL(HIP_KERNEL_NAME(gemm_bt<0>), grid, blk, 0, st, A, BT, C, res, bias, M, N, K, rpbi, rpbo, roff);
      break;
    case 1:
      hipLaunchKernelGGL(HIP_KERNEL_NAME(gemm_bt<1>), grid, blk, 0, st, A, BT, C, res, bias, M, N, K, rpbi, rpbo, roff);
      break;
    default:
      hipLaunchKernelGGL(HIP_KERNEL_NAME(gemm_bt<2>), grid, blk, 0, st, A, BT, C, res, bias, M, N, K, rpbi, rpbo, roff);
      break;
  }
}

extern "C" void kernel_launch(void* const* d_in, const int* in_sizes, int n_in,
                              void* d_out, int out_size, void* d_ws, size_t ws_size,
                              hipStream_t stream) {
  const float* x       = (const float*)d_in[0];
  const float* ctx     = (const float*)d_in[1];
  const float* pa_ng   = (const float*)d_in[2];
  const float* pa_nb   = (const float*)d_in[3];
  const float* pa_cg   = (const float*)d_in[4];
  const float* pa_cb   = (const float*)d_in[5];
  const float* pa_wq   = (const float*)d_in[6];
  const float* pa_wkv  = (const float*)d_in[7];
  const float* pa_wo   = (const float*)d_in[8];
  const float* pa_wob  = (const float*)d_in[9];
  const float* pf_g    = (const float*)d_in[10];
  const float* pf_b    = (const float*)d_in[11];
  const float* pf_w1   = (const float*)d_in[12];
  const float* pf_w2   = (const float*)d_in[13];
  const float* sa_g    = (const float*)d_in[14];
  const float* sa_b    = (const float*)d_in[15];
  const float* sa_wqkv = (const float*)d_in[16];
  const float* sa_wo   = (const float*)d_in[17];
  const float* sf_g    = (const float*)d_in[18];
  const float* sf_b    = (const float*)d_in[19];
  const float* sf_w1   = (const float*)d_in[20];
  const float* sf_w2   = (const float*)d_in[21];
  float* xo = (float*)d_out;

  char* ws = (char*)d_ws;
  size_t off = 0;
  auto alloc = [&](size_t bytes) -> char* {
    char* p = ws + off;
    off += (bytes + 255) & ~(size_t)255;
    return p;
  };

  bf16* wqT    = (bf16*)alloc((size_t)512 * 512 * 2);
  bf16* wkvT   = (bf16*)alloc((size_t)1024 * 512 * 2);
  bf16* woT    = (bf16*)alloc((size_t)512 * 512 * 2);
  bf16* w1T    = (bf16*)alloc((size_t)2048 * 512 * 2);
  bf16* w2T    = (bf16*)alloc((size_t)512 * 2048 * 2);
  bf16* saqkvT = (bf16*)alloc((size_t)L_ * 1536 * 512 * 2);
  bf16* sawoT  = (bf16*)alloc((size_t)L_ * 512 * 512 * 2);
  bf16* sfw1T  = (bf16*)alloc((size_t)L_ * 2048 * 512 * 2);
  bf16* sfw2T  = (bf16*)alloc((size_t)L_ * 512 * 2048 * 2);
  bf16* xn    = (bf16*)alloc((size_t)4096 * 512 * 2);
  bf16* reg1  = (bf16*)alloc((size_t)12288 * 512 * 2);
  bf16* qb    = (bf16*)alloc((size_t)4096 * 512 * 2);
  bf16* reg2  = (bf16*)alloc((size_t)B_ * 4096 * 1024 * 2);
  bf16* vtb   = (bf16*)alloc((size_t)B_ * H_ * 64 * 4096 * 2);
  bf16* attnb = (bf16*)alloc((size_t)4096 * 512 * 2);
  bf16* cn = reg1;
  bf16* qkvb = reg1;
  bf16* kvb = reg2;
  bf16* ffh = reg2;
  (void)ws_size; (void)in_sizes; (void)n_in; (void)out_size;

  dim3 b64(64, 4, 1);
  wtrans_kernel<<<dim3(8, 8), b64, 0, stream>>>(pa_wq, wqT, 512, 512);
  wtrans_kernel<<<dim3(16, 8), b64, 0, stream>>>(pa_wkv, wkvT, 512, 1024);
  wtrans_kernel<<<dim3(8, 8), b64, 0, stream>>>(pa_wo, woT, 512, 512);
  wtrans_kernel<<<dim3(32, 8), b64, 0, stream>>>(pf_w1, w1T, 512, 2048);
  wtrans_kernel<<<dim3(8, 32), b64, 0, stream>>>(pf_w2, w2T, 2048, 512);
  for (int l = 0; l < L_; l++) {
    wtrans_kernel<<<dim3(24, 8), b64, 0, stream>>>(sa_wqkv + (size_t)l * 512 * 1536,
                                                   saqkvT + (size_t)l * 1536 * 512, 512, 1536);
    wtrans_kernel<<<dim3(8, 8), b64, 0, stream>>>(sa_wo + (size_t)l * 512 * 512,
                                                  sawoT + (size_t)l * 512 * 512, 512, 512);
    wtrans_kernel<<<dim3(32, 8), b64, 0, stream>>>(sf_w1 + (size_t)l * 512 * 2048,
                                                   sfw1T + (size_t)l * 2048 * 512, 512, 2048);
    wtrans_kernel<<<dim3(8, 32), b64, 0, stream>>>(sf_w2 + (size_t)l * 2048 * 512,
                                                   sfw2T + (size_t)l * 512 * 2048, 2048, 512);
  }

  // ---- prefix attention block ----
  ln_kernel<<<1024, 256, 0, stream>>>(x, pa_ng, pa_nb, xn, 4096);
  ln_kernel<<<3072, 256, 0, stream>>>(ctx, pa_cg, pa_cb, cn, 12288);
  launch_gemm(stream, 0, xn, wqT, qb, nullptr, nullptr, 4096, 512, 512, 4096, 4096, 0);
  launch_gemm(stream, 0, cn, wkvT, kvb, nullptr, nullptr, 12288, 1024, 512, 3072, 4096, 0);
  launch_gemm(stream, 0, xn, wkvT, kvb, nullptr, nullptr, 4096, 1024, 512, 1024, 4096, 3072);
  vtrans_kernel<<<dim3(64, H_, B_), b64, 0, stream>>>(kvb, vtb, 4096, 1024, 512);
  attn_kernel<<<dim3(QN / 64, H_, B_), 256, 0, stream>>>(qb, 512, kvb, 1024, vtb, attnb, 4096, MCTX);
  launch_gemm(stream, 2, attnb, woT, xo, x, pa_wob, 4096, 512, 512, 4096, 4096, 0);
  ln_kernel<<<1024, 256, 0, stream>>>(xo, pf_g, pf_b, xn, 4096);
  launch_gemm(stream, 1, xn, w1T, ffh, nullptr, nullptr, 4096, 2048, 512, 4096, 4096, 0);
  launch_gemm(stream, 2, ffh, w2T, xo, xo, nullptr, 4096, 512, 2048, 4096, 4096, 0);

  // ---- depth x (self-attn + FF) ----
  for (int l = 0; l < L_; l++) {
    ln_kernel<<<1024, 256, 0, stream>>>(xo, sa_g + l * 512, sa_b + l * 512, xn, 4096);
    launch_gemm(stream, 0, xn, saqkvT + (size_t)l * 1536 * 512, qkvb, nullptr, nullptr,
                4096, 1536, 512, 4096, 4096, 0);
    vtrans_kernel<<<dim3(16, H_, B_), b64, 0, stream>>>(qkvb, vtb, 1024, 1536, 1024);
    attn_kernel<<<dim3(QN / 64, H_, B_), 256, 0, stream>>>(qkvb, 1536, qkvb + 512, 1536,
                                                           vtb, attnb, 1024, 0);
    launch_gemm(stream, 2, attnb, sawoT + (size_t)l * 512 * 512, xo, xo, nullptr,
                4096, 512, 512, 4096, 4096, 0);
    ln_kernel<<<1024, 256, 0, stream>>>(xo, sf_g + l * 512, sf_b + l * 512, xn, 4096);
    launch_gemm(stream, 1, xn, sfw1T + (size_t)l * 2048 * 512, ffh, nullptr, nullptr,
                4096, 2048, 512, 4096, 4096, 0);
    launch_gemm(stream, 2, ffh, sfw2T + (size_t)l * 512 * 2048, xo, xo, nullptr,
                4096, 512, 2048, 4096, 4096, 0);
  }
}

// Round 3
// 972.116 us; speedup vs baseline: 1.7444x; 1.4170x over previous
//
#include <hip/hip_runtime.h>
#include <hip/hip_bf16.h>
#include <cstdint>
#include <cstddef>

typedef __bf16 bf16;
typedef __attribute__((ext_vector_type(8))) __bf16 bf16x8;
typedef __attribute__((ext_vector_type(4))) __bf16 bf16x4;
typedef __attribute__((ext_vector_type(4))) float f32x4;

constexpr int B_ = 4, QN = 1024, MCTX = 3072, D_ = 512, H_ = 8, DHE = 64, L_ = 6, FF_ = 2048;
constexpr float SCALE_ = 0.125f;  // 64^-0.5

__device__ __forceinline__ f32x4 mfma16(bf16x8 a, bf16x8 b, f32x4 c) {
  return __builtin_amdgcn_mfma_f32_16x16x32_bf16(a, b, c, 0, 0, 0);
}

__device__ __forceinline__ void gl_lds16(const bf16* g, bf16* l) {
  __builtin_amdgcn_global_load_lds((const __attribute__((address_space(1))) void*)g,
                                   (__attribute__((address_space(3))) void*)l, 16, 0, 0);
}

// ---------------- LayerNorm: fp32 in -> bf16 out, one wave per row (D=512) ----
__global__ __launch_bounds__(256) void ln_kernel(const float* __restrict__ x,
                                                 const float* __restrict__ g,
                                                 const float* __restrict__ b,
                                                 bf16* __restrict__ out, int rows) {
  int wid = threadIdx.x >> 6, lane = threadIdx.x & 63;
  int row = blockIdx.x * 4 + wid;
  if (row >= rows) return;
  const float* xr = x + (size_t)row * D_;
  f32x4 a0 = *(const f32x4*)(xr + lane * 8);
  f32x4 a1 = *(const f32x4*)(xr + lane * 8 + 4);
  float s = 0.f;
#pragma unroll
  for (int i = 0; i < 4; i++) { s += a0[i]; s += a1[i]; }
#pragma unroll
  for (int d = 1; d < 64; d <<= 1) s += __shfl_xor(s, d);
  float mean = s * (1.0f / 512.0f);
  float q = 0.f;
#pragma unroll
  for (int i = 0; i < 4; i++) {
    float t0 = a0[i] - mean, t1 = a1[i] - mean;
    q += t0 * t0 + t1 * t1;
  }
#pragma unroll
  for (int d = 1; d < 64; d <<= 1) q += __shfl_xor(q, d);
  float rstd = rsqrtf(q * (1.0f / 512.0f) + 1e-5f);
  f32x4 g0 = *(const f32x4*)(g + lane * 8);
  f32x4 g1 = *(const f32x4*)(g + lane * 8 + 4);
  f32x4 b0 = *(const f32x4*)(b + lane * 8);
  f32x4 b1 = *(const f32x4*)(b + lane * 8 + 4);
  bf16x8 o;
#pragma unroll
  for (int i = 0; i < 4; i++) {
    o[i] = (bf16)((a0[i] - mean) * rstd * g0[i] + b0[i]);
    o[i + 4] = (bf16)((a1[i] - mean) * rstd * g1[i] + b1[i]);
  }
  *(bf16x8*)(out + (size_t)row * D_ + lane * 8) = o;
}

// ------------- batched weight transpose fp32 [K][N] -> bf16 [N][K] ------------
struct WDesc { const float* src; bf16* dst; int K; int N; int tstart; };
struct WPack { WDesc d[30]; int n; };

__global__ __launch_bounds__(256) void wtrans_all(WPack p) {
  __shared__ float tile[64][65];
  const int bid = blockIdx.x;
  int mi = 0;
  for (int i = 1; i < p.n; i++)
    if (p.d[i].tstart <= bid) mi = i;
  const float* src = p.d[mi].src;
  bf16* dst = p.d[mi].dst;
  const int K = p.d[mi].K, N = p.d[mi].N;
  const int lt = bid - p.d[mi].tstart;
  const int ntx = N >> 6;
  const int n0 = (lt % ntx) * 64, k0 = (lt / ntx) * 64;
  const int tx = threadIdx.x, ty = threadIdx.y;
#pragma unroll
  for (int pp = 0; pp < 16; pp++)
    tile[pp * 4 + ty][tx] = src[(size_t)(k0 + pp * 4 + ty) * N + n0 + tx];
  __syncthreads();
#pragma unroll
  for (int pp = 0; pp < 16; pp++)
    dst[(size_t)(n0 + pp * 4 + ty) * K + k0 + tx] = (bf16)tile[tx][pp * 4 + ty];
}

// ------------- V repack: [b,s,stride] (col off) -> VT [b,h,dh,Skv], bf16 ------
__global__ __launch_bounds__(256) void vtrans_kernel(const bf16* __restrict__ src,
                                                     bf16* __restrict__ vt,
                                                     int Skv, int rstride, int coloff) {
  __shared__ bf16 tile[64][65];
  int tx = threadIdx.x, ty = threadIdx.y;
  int s0 = blockIdx.x * 64, h = blockIdx.y, b = blockIdx.z;
  const bf16* sp = src + (size_t)b * Skv * rstride + coloff + h * 64;
#pragma unroll
  for (int p = 0; p < 16; p++)
    tile[p * 4 + ty][tx] = sp[(size_t)(s0 + p * 4 + ty) * rstride + tx];
  __syncthreads();
  bf16* op = vt + ((size_t)(b * H_ + h) * 64) * Skv;
#pragma unroll
  for (int p = 0; p < 16; p++)
    op[(size_t)(p * 4 + ty) * Skv + s0 + tx] = tile[tx][p * 4 + ty];
}

// ------------- GEMM 128x128 tile (m97): A[M][K] x BT[N][K] -> C ---------------
template <int EPI>
__global__ __launch_bounds__(256) void gemm_bt(const bf16* __restrict__ A,
                                               const bf16* __restrict__ BT,
                                               void* __restrict__ Cout,
                                               const float* __restrict__ resid,
                                               const float* __restrict__ bias,
                                               int M, int N, int K,
                                               int rpbi, int rpbo, int roff) {
  __shared__ bf16 smA[128 * 32];
  __shared__ bf16 smB[128 * 32];
  const int tid = threadIdx.x, wid = tid >> 6, lane = tid & 63;
  const int lr = lane & 15, lg = lane >> 4;
  const int tm = blockIdx.y * 128, tn = blockIdx.x * 128;
  const int wr = (wid >> 1) * 64, wc = (wid & 1) * 64;
  const int c0 = wid * 2;
  const int srow = lane >> 2, scol = (lane & 3) * 8;

  const bf16* gA0 = A + (size_t)(tm + c0 * 16 + srow) * K + scol;
  const bf16* gA1 = gA0 + (size_t)16 * K;
  const bf16* gB0 = BT + (size_t)(tn + c0 * 16 + srow) * K + scol;
  const bf16* gB1 = gB0 + (size_t)16 * K;
  bf16* lA0 = smA + c0 * 512;
  bf16* lA1 = lA0 + 512;
  bf16* lB0 = smB + c0 * 512;
  bf16* lB1 = lB0 + 512;

  f32x4 acc[4][4] = {};

  for (int kt = 0; kt < K; kt += 32) {
    gl_lds16(gA0 + kt, lA0);
    gl_lds16(gA1 + kt, lA1);
    gl_lds16(gB0 + kt, lB0);
    gl_lds16(gB1 + kt, lB1);
    __syncthreads();
    bf16x8 af[4], bfv[4];
#pragma unroll
    for (int i = 0; i < 4; i++)
      af[i] = *(const bf16x8*)(smA + (wr + i * 16 + lr) * 32 + lg * 8);
#pragma unroll
    for (int j = 0; j < 4; j++)
      bfv[j] = *(const bf16x8*)(smB + (wc + j * 16 + lr) * 32 + lg * 8);
#pragma unroll
    for (int i = 0; i < 4; i++)
#pragma unroll
      for (int j = 0; j < 4; j++)
        acc[i][j] = mfma16(af[i], bfv[j], acc[i][j]);
    __syncthreads();
  }

#pragma unroll
  for (int i = 0; i < 4; i++) {
#pragma unroll
    for (int r = 0; r < 4; r++) {
      int row = tm + wr + i * 16 + lg * 4 + r;
      int orow = (row / rpbi) * rpbo + (row % rpbi) + roff;
#pragma unroll
      for (int j = 0; j < 4; j++) {
        int col = tn + wc + j * 16 + lr;
        float v = acc[i][j][r];
        if (EPI == 0) {
          ((bf16*)Cout)[(size_t)orow * N + col] = (bf16)v;
        } else if (EPI == 1) {
          float gv = 0.5f * v * (1.0f + erff(v * 0.70710678118f));
          ((bf16*)Cout)[(size_t)orow * N + col] = (bf16)gv;
        } else {
          if (bias) v += bias[col];
          v += resid[(size_t)orow * N + col];
          ((float*)Cout)[(size_t)orow * N + col] = v;
        }
      }
    }
  }
}

// ------------- GEMM 64x64 tile, BK=64, dbuf, swizzled LDS (for small-N) -------
// Stage: wave w chunk j covers rows (2w+j)*8..+8; lane l -> row +(l>>3),
// k-slot stored at lds slot (l&7) == global slot ((l&7) ^ (l>>3))  [XOR swizzle]
// Read: row r, want slot t=kk*4+lg -> lds slot t ^ (r&7).
template <int EPI>
__global__ __launch_bounds__(256) void gemm64(const bf16* __restrict__ A,
                                              const bf16* __restrict__ BT,
                                              void* __restrict__ Cout,
                                              const float* __restrict__ resid,
                                              const float* __restrict__ bias,
                                              int M, int N, int K,
                                              int rpbi, int rpbo, int roff) {
  __shared__ bf16 smA[2][64 * 64];
  __shared__ bf16 smB[2][64 * 64];
  const int tid = threadIdx.x, wid = tid >> 6, lane = tid & 63;
  const int lr = lane & 15, lg = lane >> 4;
  const int tm = blockIdx.y * 64, tn = blockIdx.x * 64;
  const int wr = (wid >> 1) * 32, wc = (wid & 1) * 32;

  // per-lane pre-swizzled global source offsets
  const int l3 = lane >> 3;               // 0..7
  const int kslot = ((lane & 7) ^ l3) * 8;  // swizzled k-offset within 64
  const int row0 = 2 * wid * 8 + l3;      // chunk j=0 row
  const bf16* gA0 = A + (size_t)(tm + row0) * K + kslot;
  const bf16* gA1 = A + (size_t)(tm + row0 + 8) * K + kslot;
  const bf16* gB0 = BT + (size_t)(tn + row0) * K + kslot;
  const bf16* gB1 = BT + (size_t)(tn + row0 + 8) * K + kslot;

  f32x4 acc[2][2] = {};
  const int nt = K >> 6;

  auto stage = [&](int bi, int kt) {
    gl_lds16(gA0 + kt, &smA[bi][(2 * wid) * 512]);
    gl_lds16(gA1 + kt, &smA[bi][(2 * wid + 1) * 512]);
    gl_lds16(gB0 + kt, &smB[bi][(2 * wid) * 512]);
    gl_lds16(gB1 + kt, &smB[bi][(2 * wid + 1) * 512]);
  };

  stage(0, 0);
  __syncthreads();
  int buf = 0;
  for (int t = 0; t < nt; ++t) {
    if (t + 1 < nt) stage(buf ^ 1, (t + 1) * 64);
    bf16x8 af[2][2], bfr[2][2];
#pragma unroll
    for (int i = 0; i < 2; i++) {
      const int row = wr + i * 16 + lr;
#pragma unroll
      for (int kk = 0; kk < 2; kk++)
        af[i][kk] = *(const bf16x8*)(&smA[buf][row * 64 + (((kk * 4 + lg) ^ (row & 7)) * 8)]);
    }
#pragma unroll
    for (int j = 0; j < 2; j++) {
      const int row = wc + j * 16 + lr;
#pragma unroll
      for (int kk = 0; kk < 2; kk++)
        bfr[j][kk] = *(const bf16x8*)(&smB[buf][row * 64 + (((kk * 4 + lg) ^ (row & 7)) * 8)]);
    }
#pragma unroll
    for (int kk = 0; kk < 2; kk++)
#pragma unroll
      for (int i = 0; i < 2; i++)
#pragma unroll
        for (int j = 0; j < 2; j++)
          acc[i][j] = mfma16(af[i][kk], bfr[j][kk], acc[i][j]);
    __syncthreads();
    buf ^= 1;
  }

#pragma unroll
  for (int i = 0; i < 2; i++) {
#pragma unroll
    for (int r = 0; r < 4; r++) {
      int row = tm + wr + i * 16 + lg * 4 + r;
      int orow = (row / rpbi) * rpbo + (row % rpbi) + roff;
#pragma unroll
      for (int j = 0; j < 2; j++) {
        int col = tn + wc + j * 16 + lr;
        float v = acc[i][j][r];
        if (EPI == 0) {
          ((bf16*)Cout)[(size_t)orow * N + col] = (bf16)v;
        } else if (EPI == 1) {
          float gv = 0.5f * v * (1.0f + erff(v * 0.70710678118f));
          ((bf16*)Cout)[(size_t)orow * N + col] = (bf16)gv;
        } else {
          if (bias) v += bias[col];
          v += resid[(size_t)orow * N + col];
          ((float*)Cout)[(size_t)orow * N + col] = v;
        }
      }
    }
  }
}

// ------------- flash attention: swapped QK^T, 64-key LDS-staged tiles ---------
__global__ __launch_bounds__(256) void attn_kernel(const bf16* __restrict__ q, int qstride,
                                                   const bf16* __restrict__ k, int kstride,
                                                   const bf16* __restrict__ vt,
                                                   bf16* __restrict__ out,
                                                   int Skv, int Moff) {
  __shared__ bf16 kls[2][4096];
  __shared__ bf16 vls[2][4096];
  __shared__ bf16 pls[4][1024];

  const int tid = threadIdx.x, wid = tid >> 6, lane = tid & 63;
  const int lr = lane & 15, lg = lane >> 4, lg4 = lg * 4;
  const int b = blockIdx.z, h = blockIdx.y;
  const int q0b = blockIdx.x * 64;
  const int q0w = q0b + wid * 16;

  const int ss = (tid >> 6) & 1;
  const int sel = ss * 32 + ((tid >> 4) & 3) * 8;
  const int srow0 = (tid >> 7) * 16 + (tid & 15);
  const bf16* kbase = k + (size_t)b * Skv * kstride + h * DHE + sel;
  const bf16* vbase = vt + (size_t)((b * H_ + h) * DHE) * Skv + sel;

  const bf16* qp = q + (size_t)(b * QN + q0w + lr) * qstride + h * DHE;
  bf16x8 qa0 = *(const bf16x8*)(qp + lg * 8);
  bf16x8 qa1 = *(const bf16x8*)(qp + 32 + lg * 8);
#pragma unroll
  for (int i = 0; i < 8; i++) {
    qa0[i] = (bf16)((float)qa0[i] * SCALE_);
    qa1[i] = (bf16)((float)qa1[i] * SCALE_);
  }

  f32x4 o[4] = {};
  float mr = -3e38f, lrun = 0.f;

  int jmaxb = Moff + q0b + 63;
  if (jmaxb > Skv - 1) jmaxb = Skv - 1;
  const int nt = jmaxb / 64 + 1;

  auto stage = [&](int bi, int j0) {
    gl_lds16(kbase + (size_t)(j0 + srow0) * kstride, &kls[bi][wid * 512]);
    gl_lds16(kbase + (size_t)(j0 + srow0 + 32) * kstride, &kls[bi][2048 + wid * 512]);
    gl_lds16(vbase + (size_t)srow0 * Skv + j0, &vls[bi][wid * 512]);
    gl_lds16(vbase + (size_t)(srow0 + 32) * Skv + j0, &vls[bi][2048 + wid * 512]);
  };

  stage(0, 0);
  __syncthreads();
  int buf = 0;
  bf16* pw = &pls[wid][0];

  for (int t = 0; t < nt; ++t) {
    if (t + 1 < nt) stage(buf ^ 1, (t + 1) * 64);
    const int j0 = t * 64;
    const bf16* kbp = &kls[buf][0];
    const bf16* vbp = &vls[buf][0];

    f32x4 sv[4];
    __builtin_amdgcn_s_setprio(1);
#pragma unroll
    for (int kg = 0; kg < 4; kg++) {
      bf16x8 k0 = *(const bf16x8*)(kbp + (kg * 128 + lane) * 8);
      bf16x8 k1 = *(const bf16x8*)(kbp + (kg * 128 + 64 + lane) * 8);
      f32x4 z = {0.f, 0.f, 0.f, 0.f};
      z = mfma16(k0, qa0, z);
      z = mfma16(k1, qa1, z);
      sv[kg] = z;
    }
    __builtin_amdgcn_s_setprio(0);
    const bool full = (j0 + 63 <= Moff + q0w);
    if (!full) {
      const int limq = Moff + q0w + lr;
#pragma unroll
      for (int kg = 0; kg < 4; kg++)
#pragma unroll
        for (int r = 0; r < 4; r++)
          if (j0 + kg * 16 + lg4 + r > limq) sv[kg][r] = -3e38f;
    }
    float pmax = sv[0][0];
#pragma unroll
    for (int kg = 0; kg < 4; kg++)
#pragma unroll
      for (int r = 0; r < 4; r++) pmax = fmaxf(pmax, sv[kg][r]);
    pmax = fmaxf(pmax, __shfl_xor(pmax, 16));
    pmax = fmaxf(pmax, __shfl_xor(pmax, 32));
    if (__any(pmax > mr + 8.f)) {
      float mn = fmaxf(mr, pmax);
      float scl = __expf(mr - mn);
      mr = mn;
      lrun *= scl;
      float c0 = __shfl(scl, lg4 + 0), c1 = __shfl(scl, lg4 + 1);
      float c2 = __shfl(scl, lg4 + 2), c3 = __shfl(scl, lg4 + 3);
#pragma unroll
      for (int f = 0; f < 4; f++) {
        o[f][0] *= c0; o[f][1] *= c1; o[f][2] *= c2; o[f][3] *= c3;
      }
    }
    float rsum = 0.f;
#pragma unroll
    for (int kg = 0; kg < 4; kg++) {
      float p0 = __expf(sv[kg][0] - mr);
      float p1 = __expf(sv[kg][1] - mr);
      float p2 = __expf(sv[kg][2] - mr);
      float p3 = __expf(sv[kg][3] - mr);
      rsum += (p0 + p1) + (p2 + p3);
      bf16x4 pk = {(bf16)p0, (bf16)p1, (bf16)p2, (bf16)p3};
      const int k8 = kg * 2 + (lg >> 1);
      *(bf16x4*)(pw + ((k8 >> 2) * 64 + (k8 & 3) * 16 + lr) * 8 + (lg & 1) * 4) = pk;
    }
    rsum += __shfl_xor(rsum, 16);
    rsum += __shfl_xor(rsum, 32);
    lrun += rsum;
    bf16x8 pa0 = *(const bf16x8*)(pw + lane * 8);
    bf16x8 pa1 = *(const bf16x8*)(pw + (64 + lane) * 8);
    __builtin_amdgcn_s_setprio(1);
#pragma unroll
    for (int f = 0; f < 4; f++) {
      bf16x8 v0 = *(const bf16x8*)(vbp + (f * 128 + lane) * 8);
      bf16x8 v1 = *(const bf16x8*)(vbp + (f * 128 + 64 + lane) * 8);
      o[f] = mfma16(pa0, v0, o[f]);
      o[f] = mfma16(pa1, v1, o[f]);
    }
    __builtin_amdgcn_s_setprio(0);
    __syncthreads();
    buf ^= 1;
  }

  float linv = 1.0f / lrun;
  float li[4];
#pragma unroll
  for (int r = 0; r < 4; r++) li[r] = __shfl(linv, lg4 + r);
#pragma unroll
  for (int f = 0; f < 4; f++)
#pragma unroll
    for (int r = 0; r < 4; r++)
      out[(size_t)(b * QN + q0w + lg4 + r) * D_ + h * DHE + f * 16 + lr] =
          (bf16)(o[f][r] * li[r]);
}

// -----------------------------------------------------------------------------
static void launch_gemm(hipStream_t st, int epi, const bf16* A, const bf16* BT, void* C,
                        const float* res, const float* bias,
                        int M, int N, int K, int rpbi, int rpbo, int roff) {
  if (N <= 1024) {
    dim3 grid(N / 64, M / 64), blk(256, 1, 1);
    switch (epi) {
      case 0:
        hipLaunchKernelGGL(HIP_KERNEL_NAME(gemm64<0>), grid, blk, 0, st, A, BT, C, res, bias, M, N, K, rpbi, rpbo, roff);
        break;
      case 1:
        hipLaunchKernelGGL(HIP_KERNEL_NAME(gemm64<1>), grid, blk, 0, st, A, BT, C, res, bias, M, N, K, rpbi, rpbo, roff);
        break;
      default:
        hipLaunchKernelGGL(HIP_KERNEL_NAME(gemm64<2>), grid, blk, 0, st, A, BT, C, res, bias, M, N, K, rpbi, rpbo, roff);
        break;
    }
    return;
  }
  dim3 grid(N / 128, M / 128), blk(256, 1, 1);
  switch (epi) {
    case 0:
      hipLaunchKernelGGL(HIP_KERNEL_NAME(gemm_bt<0>), grid, blk, 0, st, A, BT, C, res, bias, M, N, K, rpbi, rpbo, roff);
      break;
    case 1:
      hipLaunchKernelGGL(HIP_KERNEL_NAME(gemm_bt<1>), grid, blk, 0, st, A, BT, C, res, bias, M, N, K, rpbi, rpbo, roff);
      break;
    default:
      hipLaunchKernelGGL(HIP_KERNEL_NAME(gemm_bt<2>), grid, blk, 0, st, A, BT, C, res, bias, M, N, K, rpbi, rpbo, roff);
      break;
  }
}

extern "C" void kernel_launch(void* const* d_in, const int* in_sizes, int n_in,
                              void* d_out, int out_size, void* d_ws, size_t ws_size,
                              hipStream_t stream) {
  const float* x       = (const float*)d_in[0];
  const float* ctx     = (const float*)d_in[1];
  const float* pa_ng   = (const float*)d_in[2];
  const float* pa_nb   = (const float*)d_in[3];
  const float* pa_cg   = (const float*)d_in[4];
  const float* pa_cb   = (const float*)d_in[5];
  const float* pa_wq   = (const float*)d_in[6];
  const float* pa_wkv  = (const float*)d_in[7];
  const float* pa_wo   = (const float*)d_in[8];
  const float* pa_wob  = (const float*)d_in[9];
  const float* pf_g    = (const float*)d_in[10];
  const float* pf_b    = (const float*)d_in[11];
  const float* pf_w1   = (const float*)d_in[12];
  const float* pf_w2   = (const float*)d_in[13];
  const float* sa_g    = (const float*)d_in[14];
  const float* sa_b    = (const float*)d_in[15];
  const float* sa_wqkv = (const float*)d_in[16];
  const float* sa_wo   = (const float*)d_in[17];
  const float* sf_g    = (const float*)d_in[18];
  const float* sf_b    = (const float*)d_in[19];
  const float* sf_w1   = (const float*)d_in[20];
  const float* sf_w2   = (const float*)d_in[21];
  float* xo = (float*)d_out;

  char* ws = (char*)d_ws;
  size_t off = 0;
  auto alloc = [&](size_t bytes) -> char* {
    char* p = ws + off;
    off += (bytes + 255) & ~(size_t)255;
    return p;
  };

  bf16* wqT    = (bf16*)alloc((size_t)512 * 512 * 2);
  bf16* wkvT   = (bf16*)alloc((size_t)1024 * 512 * 2);
  bf16* woT    = (bf16*)alloc((size_t)512 * 512 * 2);
  bf16* w1T    = (bf16*)alloc((size_t)2048 * 512 * 2);
  bf16* w2T    = (bf16*)alloc((size_t)512 * 2048 * 2);
  bf16* saqkvT = (bf16*)alloc((size_t)L_ * 1536 * 512 * 2);
  bf16* sawoT  = (bf16*)alloc((size_t)L_ * 512 * 512 * 2);
  bf16* sfw1T  = (bf16*)alloc((size_t)L_ * 2048 * 512 * 2);
  bf16* sfw2T  = (bf16*)alloc((size_t)L_ * 512 * 2048 * 2);
  bf16* xn    = (bf16*)alloc((size_t)4096 * 512 * 2);
  bf16* reg1  = (bf16*)alloc((size_t)12288 * 512 * 2);
  bf16* qb    = (bf16*)alloc((size_t)4096 * 512 * 2);
  bf16* reg2  = (bf16*)alloc((size_t)B_ * 4096 * 1024 * 2);
  bf16* vtb   = (bf16*)alloc((size_t)B_ * H_ * 64 * 4096 * 2);
  bf16* attnb = (bf16*)alloc((size_t)4096 * 512 * 2);
  bf16* cn = reg1;
  bf16* qkvb = reg1;
  bf16* kvb = reg2;
  bf16* ffh = reg2;
  (void)ws_size; (void)in_sizes; (void)n_in; (void)out_size;

  // ---- batched weight prep (one dispatch) ----
  WPack wp;
  int nt_acc = 0, wi = 0;
  auto addw = [&](const float* s, bf16* d, int K, int N) {
    wp.d[wi].src = s; wp.d[wi].dst = d; wp.d[wi].K = K; wp.d[wi].N = N;
    wp.d[wi].tstart = nt_acc;
    nt_acc += (N / 64) * (K / 64);
    wi++;
  };
  addw(pa_wq, wqT, 512, 512);
  addw(pa_wkv, wkvT, 512, 1024);
  addw(pa_wo, woT, 512, 512);
  addw(pf_w1, w1T, 512, 2048);
  addw(pf_w2, w2T, 2048, 512);
  for (int l = 0; l < L_; l++) {
    addw(sa_wqkv + (size_t)l * 512 * 1536, saqkvT + (size_t)l * 1536 * 512, 512, 1536);
    addw(sa_wo + (size_t)l * 512 * 512, sawoT + (size_t)l * 512 * 512, 512, 512);
    addw(sf_w1 + (size_t)l * 512 * 2048, sfw1T + (size_t)l * 2048 * 512, 512, 2048);
    addw(sf_w2 + (size_t)l * 2048 * 512, sfw2T + (size_t)l * 512 * 2048, 2048, 512);
  }
  wp.n = wi;
  wtrans_all<<<nt_acc, dim3(64, 4, 1), 0, stream>>>(wp);

  // ---- prefix attention block ----
  ln_kernel<<<1024, 256, 0, stream>>>(x, pa_ng, pa_nb, xn, 4096);
  ln_kernel<<<3072, 256, 0, stream>>>(ctx, pa_cg, pa_cb, cn, 12288);
  launch_gemm(stream, 0, xn, wqT, qb, nullptr, nullptr, 4096, 512, 512, 4096, 4096, 0);
  launch_gemm(stream, 0, cn, wkvT, kvb, nullptr, nullptr, 12288, 1024, 512, 3072, 4096, 0);
  launch_gemm(stream, 0, xn, wkvT, kvb, nullptr, nullptr, 4096, 1024, 512, 1024, 4096, 3072);
  vtrans_kernel<<<dim3(64, H_, B_), dim3(64, 4, 1), 0, stream>>>(kvb, vtb, 4096, 1024, 512);
  attn_kernel<<<dim3(QN / 64, H_, B_), 256, 0, stream>>>(qb, 512, kvb, 1024, vtb, attnb, 4096, MCTX);
  launch_gemm(stream, 2, attnb, woT, xo, x, pa_wob, 4096, 512, 512, 4096, 4096, 0);
  ln_kernel<<<1024, 256, 0, stream>>>(xo, pf_g, pf_b, xn, 4096);
  launch_gemm(stream, 1, xn, w1T, ffh, nullptr, nullptr, 4096, 2048, 512, 4096, 4096, 0);
  launch_gemm(stream, 2, ffh, w2T, xo, xo, nullptr, 4096, 512, 2048, 4096, 4096, 0);

  // ---- depth x (self-attn + FF) ----
  for (int l = 0; l < L_; l++) {
    ln_kernel<<<1024, 256, 0, stream>>>(xo, sa_g + l * 512, sa_b + l * 512, xn, 4096);
    launch_gemm(stream, 0, xn, saqkvT + (size_t)l * 1536 * 512, qkvb, nullptr, nullptr,
                4096, 1536, 512, 4096, 4096, 0);
    vtrans_kernel<<<dim3(16, H_, B_), dim3(64, 4, 1), 0, stream>>>(qkvb, vtb, 1024, 1536, 1024);
    attn_kernel<<<dim3(QN / 64, H_, B_), 256, 0, stream>>>(qkvb, 1536, qkvb + 512, 1536,
                                                           vtb, attnb, 1024, 0);
    launch_gemm(stream, 2, attnb, sawoT + (size_t)l * 512 * 512, xo, xo, nullptr,
                4096, 512, 512, 4096, 4096, 0);
    ln_kernel<<<1024, 256, 0, stream>>>(xo, sf_g + l * 512, sf_b + l * 512, xn, 4096);
    launch_gemm(stream, 1, xn, sfw1T + (size_t)l * 2048 * 512, ffh, nullptr, nullptr,
                4096, 2048, 512, 4096, 4096, 0);
    launch_gemm(stream, 2, ffh, sfw2T + (size_t)l * 512 * 2048, xo, xo, nullptr,
                4096, 512, 2048, 4096, 4096, 0);
  }
}

// Round 4
// 964.226 us; speedup vs baseline: 1.7587x; 1.0082x over previous
//
#include <hip/hip_runtime.h>
#include <hip/hip_bf16.h>
#include <cstdint>
#include <cstddef>

typedef __bf16 bf16;
typedef __attribute__((ext_vector_type(8))) __bf16 bf16x8;
typedef __attribute__((ext_vector_type(4))) __bf16 bf16x4;
typedef __attribute__((ext_vector_type(4))) float f32x4;

constexpr int B_ = 4, QN = 1024, MCTX = 3072, D_ = 512, H_ = 8, DHE = 64, L_ = 6, FF_ = 2048;
constexpr float SCALE_ = 0.125f;  // 64^-0.5

__device__ __forceinline__ f32x4 mfma16(bf16x8 a, bf16x8 b, f32x4 c) {
  return __builtin_amdgcn_mfma_f32_16x16x32_bf16(a, b, c, 0, 0, 0);
}

__device__ __forceinline__ void gl_lds16(const bf16* g, bf16* l) {
  __builtin_amdgcn_global_load_lds((const __attribute__((address_space(1))) void*)g,
                                   (__attribute__((address_space(3))) void*)l, 16, 0, 0);
}

// ---------------- LayerNorm: fp32 in -> bf16 out, one wave per row (D=512) ----
__global__ __launch_bounds__(256) void ln_kernel(const float* __restrict__ x,
                                                 const float* __restrict__ g,
                                                 const float* __restrict__ b,
                                                 bf16* __restrict__ out, int rows) {
  int wid = threadIdx.x >> 6, lane = threadIdx.x & 63;
  int row = blockIdx.x * 4 + wid;
  if (row >= rows) return;
  const float* xr = x + (size_t)row * D_;
  f32x4 a0 = *(const f32x4*)(xr + lane * 8);
  f32x4 a1 = *(const f32x4*)(xr + lane * 8 + 4);
  float s = 0.f;
#pragma unroll
  for (int i = 0; i < 4; i++) { s += a0[i]; s += a1[i]; }
#pragma unroll
  for (int d = 1; d < 64; d <<= 1) s += __shfl_xor(s, d);
  float mean = s * (1.0f / 512.0f);
  float q = 0.f;
#pragma unroll
  for (int i = 0; i < 4; i++) {
    float t0 = a0[i] - mean, t1 = a1[i] - mean;
    q += t0 * t0 + t1 * t1;
  }
#pragma unroll
  for (int d = 1; d < 64; d <<= 1) q += __shfl_xor(q, d);
  float rstd = rsqrtf(q * (1.0f / 512.0f) + 1e-5f);
  f32x4 g0 = *(const f32x4*)(g + lane * 8);
  f32x4 g1 = *(const f32x4*)(g + lane * 8 + 4);
  f32x4 b0 = *(const f32x4*)(b + lane * 8);
  f32x4 b1 = *(const f32x4*)(b + lane * 8 + 4);
  bf16x8 o;
#pragma unroll
  for (int i = 0; i < 4; i++) {
    o[i] = (bf16)((a0[i] - mean) * rstd * g0[i] + b0[i]);
    o[i + 4] = (bf16)((a1[i] - mean) * rstd * g1[i] + b1[i]);
  }
  *(bf16x8*)(out + (size_t)row * D_ + lane * 8) = o;
}

// ------------- batched weight transpose fp32 [K][N] -> bf16 [N][K] ------------
struct WDesc { const float* src; bf16* dst; int K; int N; int tstart; };
struct WPack { WDesc d[30]; int n; };

__global__ __launch_bounds__(256) void wtrans_all(WPack p) {
  __shared__ float tile[64][65];
  const int bid = blockIdx.x;
  int mi = 0;
  for (int i = 1; i < p.n; i++)
    if (p.d[i].tstart <= bid) mi = i;
  const float* src = p.d[mi].src;
  bf16* dst = p.d[mi].dst;
  const int K = p.d[mi].K, N = p.d[mi].N;
  const int lt = bid - p.d[mi].tstart;
  const int ntx = N >> 6;
  const int n0 = (lt % ntx) * 64, k0 = (lt / ntx) * 64;
  const int tx = threadIdx.x, ty = threadIdx.y;
#pragma unroll
  for (int pp = 0; pp < 16; pp++)
    tile[pp * 4 + ty][tx] = src[(size_t)(k0 + pp * 4 + ty) * N + n0 + tx];
  __syncthreads();
#pragma unroll
  for (int pp = 0; pp < 16; pp++)
    dst[(size_t)(n0 + pp * 4 + ty) * K + k0 + tx] = (bf16)tile[tx][pp * 4 + ty];
}

// ------------- V repack: [b,s,stride] (col off) -> VT [b,h,dh,Skv], bf16 ------
__global__ __launch_bounds__(256) void vtrans_kernel(const bf16* __restrict__ src,
                                                     bf16* __restrict__ vt,
                                                     int Skv, int rstride, int coloff) {
  __shared__ bf16 tile[64][65];
  int tx = threadIdx.x, ty = threadIdx.y;
  int s0 = blockIdx.x * 64, h = blockIdx.y, b = blockIdx.z;
  const bf16* sp = src + (size_t)b * Skv * rstride + coloff + h * 64;
#pragma unroll
  for (int p = 0; p < 16; p++)
    tile[p * 4 + ty][tx] = sp[(size_t)(s0 + p * 4 + ty) * rstride + tx];
  __syncthreads();
  bf16* op = vt + ((size_t)(b * H_ + h) * 64) * Skv;
#pragma unroll
  for (int p = 0; p < 16; p++)
    op[(size_t)(p * 4 + ty) * Skv + s0 + tx] = tile[tx][p * 4 + ty];
}

// ------------- GEMM 64x64 tile, BK=64, 3-stage counted-vmcnt pipeline ---------
// Stage: wave w chunk j covers rows (2w+j)*8..+8; lane l -> row +(l>>3),
// k-slot at lds slot (l&7) == global slot ((l&7) ^ (l>>3))  [XOR swizzle]
// Read: row r, slot t=kk*4+lg -> lds slot t ^ (r&7).
template <int EPI>
__global__ __launch_bounds__(256) void gemm64(const bf16* __restrict__ A,
                                              const bf16* __restrict__ BT,
                                              void* __restrict__ Cout,
                                              const float* __restrict__ resid,
                                              const float* __restrict__ bias,
                                              int M, int N, int K,
                                              int rpbi, int rpbo, int roff) {
  __shared__ bf16 smA[3][64 * 64];
  __shared__ bf16 smB[3][64 * 64];
  const int tid = threadIdx.x, wid = tid >> 6, lane = tid & 63;
  const int lr = lane & 15, lg = lane >> 4;
  const int tm = blockIdx.y * 64, tn = blockIdx.x * 64;
  const int wr = (wid >> 1) * 32, wc = (wid & 1) * 32;

  const int l3 = lane >> 3;
  const int kslot = ((lane & 7) ^ l3) * 8;
  const int row0 = 2 * wid * 8 + l3;
  const bf16* gA0 = A + (size_t)(tm + row0) * K + kslot;
  const bf16* gA1 = A + (size_t)(tm + row0 + 8) * K + kslot;
  const bf16* gB0 = BT + (size_t)(tn + row0) * K + kslot;
  const bf16* gB1 = BT + (size_t)(tn + row0 + 8) * K + kslot;

  f32x4 acc[2][2] = {};
  const int nt = K >> 6;

  auto stage = [&](int bi, int kt) {
    gl_lds16(gA0 + kt, &smA[bi][(2 * wid) * 512]);
    gl_lds16(gA1 + kt, &smA[bi][(2 * wid + 1) * 512]);
    gl_lds16(gB0 + kt, &smB[bi][(2 * wid) * 512]);
    gl_lds16(gB1 + kt, &smB[bi][(2 * wid + 1) * 512]);
  };

  stage(0, 0);
  if (nt > 1) stage(1, 64);

  for (int t = 0; t < nt; ++t) {
    const int bi = t % 3;
    // wait for my stage(t) to land (stage(t+1) may remain in flight), then barrier
    if (t + 1 < nt) {
      asm volatile("s_waitcnt vmcnt(4)" ::: "memory");
    } else {
      asm volatile("s_waitcnt vmcnt(0)" ::: "memory");
    }
    __builtin_amdgcn_s_barrier();
    __builtin_amdgcn_sched_barrier(0);
    if (t + 2 < nt) stage((t + 2) % 3, (t + 2) * 64);

    bf16x8 af[2][2], bfr[2][2];
#pragma unroll
    for (int i = 0; i < 2; i++) {
      const int row = wr + i * 16 + lr;
#pragma unroll
      for (int kk = 0; kk < 2; kk++)
        af[i][kk] = *(const bf16x8*)(&smA[bi][row * 64 + (((kk * 4 + lg) ^ (row & 7)) * 8)]);
    }
#pragma unroll
    for (int j = 0; j < 2; j++) {
      const int row = wc + j * 16 + lr;
#pragma unroll
      for (int kk = 0; kk < 2; kk++)
        bfr[j][kk] = *(const bf16x8*)(&smB[bi][row * 64 + (((kk * 4 + lg) ^ (row & 7)) * 8)]);
    }
#pragma unroll
    for (int kk = 0; kk < 2; kk++)
#pragma unroll
      for (int i = 0; i < 2; i++)
#pragma unroll
        for (int j = 0; j < 2; j++)
          acc[i][j] = mfma16(af[i][kk], bfr[j][kk], acc[i][j]);
  }

#pragma unroll
  for (int i = 0; i < 2; i++) {
#pragma unroll
    for (int r = 0; r < 4; r++) {
      int row = tm + wr + i * 16 + lg * 4 + r;
      int orow = (row / rpbi) * rpbo + (row % rpbi) + roff;
#pragma unroll
      for (int j = 0; j < 2; j++) {
        int col = tn + wc + j * 16 + lr;
        float v = acc[i][j][r];
        if (EPI == 0) {
          ((bf16*)Cout)[(size_t)orow * N + col] = (bf16)v;
        } else if (EPI == 1) {
          float gv = 0.5f * v * (1.0f + erff(v * 0.70710678118f));
          ((bf16*)Cout)[(size_t)orow * N + col] = (bf16)gv;
        } else {
          if (bias) v += bias[col];
          v += resid[(size_t)orow * N + col];
          ((float*)Cout)[(size_t)orow * N + col] = v;
        }
      }
    }
  }
}

// ------------- flash attention: swapped QK^T, 64-key LDS tiles, KV-split ------
// NSPLIT>1: write partials (po bf16 [NSPLIT][B*H*QN][64], pm/pl f32) for combine.
template <int NSPLIT>
__global__ __launch_bounds__(256) void attn_kernel(const bf16* __restrict__ q, int qstride,
                                                   const bf16* __restrict__ k, int kstride,
                                                   const bf16* __restrict__ vt,
                                                   bf16* __restrict__ out,
                                                   bf16* __restrict__ po,
                                                   float* __restrict__ pm,
                                                   float* __restrict__ pl,
                                                   int Skv, int Moff, int spllen) {
  __shared__ bf16 kls[2][4096];
  __shared__ bf16 vls[2][4096];
  __shared__ bf16 pls[4][1024];

  const int tid = threadIdx.x, wid = tid >> 6, lane = tid & 63;
  const int lr = lane & 15, lg = lane >> 4, lg4 = lg * 4;
  const int b = blockIdx.z, h = blockIdx.y;
  const int qblk = blockIdx.x / NSPLIT;
  const int split = blockIdx.x % NSPLIT;
  const int q0b = qblk * 64;
  const int q0w = q0b + wid * 16;
  const int kv_lo = split * spllen;

  int jhi_blk = Moff + q0b + 63;
  if (jhi_blk > Skv - 1) jhi_blk = Skv - 1;
  int hi = kv_lo + spllen;
  if (hi > jhi_blk + 1) hi = jhi_blk + 1;
  const int ntl = (hi > kv_lo) ? ((hi - kv_lo + 63) >> 6) : 0;

  if (NSPLIT > 1 && ntl == 0) {  // inactive split: write neutral partials
    size_t rb = ((size_t)split * B_ * H_ + (size_t)b * H_ + h) * QN + q0w;
#pragma unroll
    for (int f = 0; f < 4; f++)
#pragma unroll
      for (int r = 0; r < 4; r++) po[(rb + lg4 + r) * 64 + f * 16 + lr] = (bf16)0.f;
    if (lg == 0) { pm[rb + lr] = -3e38f; pl[rb + lr] = 0.f; }
    return;
  }

  const int ss = (tid >> 6) & 1;
  const int sel = ss * 32 + ((tid >> 4) & 3) * 8;
  const int srow0 = (tid >> 7) * 16 + (tid & 15);
  const bf16* kbase = k + (size_t)b * Skv * kstride + h * DHE + sel;
  const bf16* vbase = vt + (size_t)((b * H_ + h) * DHE) * Skv + sel;

  const bf16* qp = q + (size_t)(b * QN + q0w + lr) * qstride + h * DHE;
  bf16x8 qa0 = *(const bf16x8*)(qp + lg * 8);
  bf16x8 qa1 = *(const bf16x8*)(qp + 32 + lg * 8);
#pragma unroll
  for (int i = 0; i < 8; i++) {
    qa0[i] = (bf16)((float)qa0[i] * SCALE_);
    qa1[i] = (bf16)((float)qa1[i] * SCALE_);
  }

  f32x4 o[4] = {};
  float mr = -3e38f, lrun = 0.f;

  auto stage = [&](int bi, int j0) {
    gl_lds16(kbase + (size_t)(j0 + srow0) * kstride, &kls[bi][wid * 512]);
    gl_lds16(kbase + (size_t)(j0 + srow0 + 32) * kstride, &kls[bi][2048 + wid * 512]);
    gl_lds16(vbase + (size_t)srow0 * Skv + j0, &vls[bi][wid * 512]);
    gl_lds16(vbase + (size_t)(srow0 + 32) * Skv + j0, &vls[bi][2048 + wid * 512]);
  };

  stage(0, kv_lo);
  __syncthreads();
  int buf = 0;
  bf16* pw = &pls[wid][0];

  for (int t = 0; t < ntl; ++t) {
    const int j0 = kv_lo + t * 64;
    if (t + 1 < ntl) stage(buf ^ 1, j0 + 64);
    const bf16* kbp = &kls[buf][0];
    const bf16* vbp = &vls[buf][0];

    f32x4 sv[4];
    __builtin_amdgcn_s_setprio(1);
#pragma unroll
    for (int kg = 0; kg < 4; kg++) {
      bf16x8 k0 = *(const bf16x8*)(kbp + (kg * 128 + lane) * 8);
      bf16x8 k1 = *(const bf16x8*)(kbp + (kg * 128 + 64 + lane) * 8);
      f32x4 z = {0.f, 0.f, 0.f, 0.f};
      z = mfma16(k0, qa0, z);
      z = mfma16(k1, qa1, z);
      sv[kg] = z;
    }
    __builtin_amdgcn_s_setprio(0);
    const bool full = (j0 + 63 <= Moff + q0w);
    if (!full) {
      const int limq = Moff + q0w + lr;
#pragma unroll
      for (int kg = 0; kg < 4; kg++)
#pragma unroll
        for (int r = 0; r < 4; r++)
          if (j0 + kg * 16 + lg4 + r > limq) sv[kg][r] = -3e38f;
    }
    float pmax = sv[0][0];
#pragma unroll
    for (int kg = 0; kg < 4; kg++)
#pragma unroll
      for (int r = 0; r < 4; r++) pmax = fmaxf(pmax, sv[kg][r]);
    pmax = fmaxf(pmax, __shfl_xor(pmax, 16));
    pmax = fmaxf(pmax, __shfl_xor(pmax, 32));
    if (__any(pmax > mr + 8.f)) {
      float mn = fmaxf(mr, pmax);
      float scl = __expf(mr - mn);
      mr = mn;
      lrun *= scl;
      float c0 = __shfl(scl, lg4 + 0), c1 = __shfl(scl, lg4 + 1);
      float c2 = __shfl(scl, lg4 + 2), c3 = __shfl(scl, lg4 + 3);
#pragma unroll
      for (int f = 0; f < 4; f++) {
        o[f][0] *= c0; o[f][1] *= c1; o[f][2] *= c2; o[f][3] *= c3;
      }
    }
    float rsum = 0.f;
#pragma unroll
    for (int kg = 0; kg < 4; kg++) {
      float p0 = __expf(sv[kg][0] - mr);
      float p1 = __expf(sv[kg][1] - mr);
      float p2 = __expf(sv[kg][2] - mr);
      float p3 = __expf(sv[kg][3] - mr);
      rsum += (p0 + p1) + (p2 + p3);
      bf16x4 pk = {(bf16)p0, (bf16)p1, (bf16)p2, (bf16)p3};
      const int k8 = kg * 2 + (lg >> 1);
      *(bf16x4*)(pw + ((k8 >> 2) * 64 + (k8 & 3) * 16 + lr) * 8 + (lg & 1) * 4) = pk;
    }
    rsum += __shfl_xor(rsum, 16);
    rsum += __shfl_xor(rsum, 32);
    lrun += rsum;
    bf16x8 pa0 = *(const bf16x8*)(pw + lane * 8);
    bf16x8 pa1 = *(const bf16x8*)(pw + (64 + lane) * 8);
    __builtin_amdgcn_s_setprio(1);
#pragma unroll
    for (int f = 0; f < 4; f++) {
      bf16x8 v0 = *(const bf16x8*)(vbp + (f * 128 + lane) * 8);
      bf16x8 v1 = *(const bf16x8*)(vbp + (f * 128 + 64 + lane) * 8);
      o[f] = mfma16(pa0, v0, o[f]);
      o[f] = mfma16(pa1, v1, o[f]);
    }
    __builtin_amdgcn_s_setprio(0);
    __syncthreads();
    buf ^= 1;
  }

  if (NSPLIT == 1) {
    float linv = 1.0f / lrun;
    float li[4];
#pragma unroll
    for (int r = 0; r < 4; r++) li[r] = __shfl(linv, lg4 + r);
#pragma unroll
    for (int f = 0; f < 4; f++)
#pragma unroll
      for (int r = 0; r < 4; r++)
        out[(size_t)(b * QN + q0w + lg4 + r) * D_ + h * DHE + f * 16 + lr] =
            (bf16)(o[f][r] * li[r]);
  } else {
    size_t rb = ((size_t)split * B_ * H_ + (size_t)b * H_ + h) * QN + q0w;
#pragma unroll
    for (int f = 0; f < 4; f++)
#pragma unroll
      for (int r = 0; r < 4; r++)
        po[(rb + lg4 + r) * 64 + f * 16 + lr] = (bf16)o[f][r];
    if (lg == 0) { pm[rb + lr] = mr; pl[rb + lr] = lrun; }
  }
}

// ------------- combine: merge NSPLIT partial (O,m,l) -> bf16 out --------------
template <int NSPLIT>
__global__ __launch_bounds__(256) void attn_combine(const bf16* __restrict__ po,
                                                    const float* __restrict__ pm,
                                                    const float* __restrict__ pl,
                                                    bf16* __restrict__ out) {
  constexpr int TOT = B_ * H_ * QN;
  const int wid = threadIdx.x >> 6, lane = threadIdx.x & 63;
  const int row = blockIdx.x * 4 + wid;  // (b*H+h)*QN + q
  float mv[NSPLIT], lv[NSPLIT];
  float mstar = -3e38f;
#pragma unroll
  for (int s = 0; s < NSPLIT; s++) {
    mv[s] = pm[s * TOT + row];
    lv[s] = pl[s * TOT + row];
    mstar = fmaxf(mstar, mv[s]);
  }
  float lstar = 0.f, acc = 0.f;
#pragma unroll
  for (int s = 0; s < NSPLIT; s++) {
    float w = __expf(mv[s] - mstar);
    lstar += lv[s] * w;
    acc += (float)po[((size_t)s * TOT + row) * 64 + lane] * w;
  }
  const int b = row >> 13, hq = row & 8191, h = hq >> 10, qq = hq & 1023;
  out[((size_t)b * QN + qq) * D_ + h * DHE + lane] = (bf16)(acc / lstar);
}

// -----------------------------------------------------------------------------
static void launch_gemm(hipStream_t st, int epi, const bf16* A, const bf16* BT, void* C,
                        const float* res, const float* bias,
                        int M, int N, int K, int rpbi, int rpbo, int roff) {
  dim3 grid(N / 64, M / 64), blk(256, 1, 1);
  switch (epi) {
    case 0:
      hipLaunchKernelGGL(HIP_KERNEL_NAME(gemm64<0>), grid, blk, 0, st, A, BT, C, res, bias, M, N, K, rpbi, rpbo, roff);
      break;
    case 1:
      hipLaunchKernelGGL(HIP_KERNEL_NAME(gemm64<1>), grid, blk, 0, st, A, BT, C, res, bias, M, N, K, rpbi, rpbo, roff);
      break;
    default:
      hipLaunchKernelGGL(HIP_KERNEL_NAME(gemm64<2>), grid, blk, 0, st, A, BT, C, res, bias, M, N, K, rpbi, rpbo, roff);
      break;
  }
}

extern "C" void kernel_launch(void* const* d_in, const int* in_sizes, int n_in,
                              void* d_out, int out_size, void* d_ws, size_t ws_size,
                              hipStream_t stream) {
  const float* x       = (const float*)d_in[0];
  const float* ctx     = (const float*)d_in[1];
  const float* pa_ng   = (const float*)d_in[2];
  const float* pa_nb   = (const float*)d_in[3];
  const float* pa_cg   = (const float*)d_in[4];
  const float* pa_cb   = (const float*)d_in[5];
  const float* pa_wq   = (const float*)d_in[6];
  const float* pa_wkv  = (const float*)d_in[7];
  const float* pa_wo   = (const float*)d_in[8];
  const float* pa_wob  = (const float*)d_in[9];
  const float* pf_g    = (const float*)d_in[10];
  const float* pf_b    = (const float*)d_in[11];
  const float* pf_w1   = (const float*)d_in[12];
  const float* pf_w2   = (const float*)d_in[13];
  const float* sa_g    = (const float*)d_in[14];
  const float* sa_b    = (const float*)d_in[15];
  const float* sa_wqkv = (const float*)d_in[16];
  const float* sa_wo   = (const float*)d_in[17];
  const float* sf_g    = (const float*)d_in[18];
  const float* sf_b    = (const float*)d_in[19];
  const float* sf_w1   = (const float*)d_in[20];
  const float* sf_w2   = (const float*)d_in[21];
  float* xo = (float*)d_out;

  char* ws = (char*)d_ws;
  size_t off = 0;
  auto alloc = [&](size_t bytes) -> char* {
    char* p = ws + off;
    off += (bytes + 255) & ~(size_t)255;
    return p;
  };

  bf16* wqT    = (bf16*)alloc((size_t)512 * 512 * 2);
  bf16* wkvT   = (bf16*)alloc((size_t)1024 * 512 * 2);
  bf16* woT    = (bf16*)alloc((size_t)512 * 512 * 2);
  bf16* w1T    = (bf16*)alloc((size_t)2048 * 512 * 2);
  bf16* w2T    = (bf16*)alloc((size_t)512 * 2048 * 2);
  bf16* saqkvT = (bf16*)alloc((size_t)L_ * 1536 * 512 * 2);
  bf16* sawoT  = (bf16*)alloc((size_t)L_ * 512 * 512 * 2);
  bf16* sfw1T  = (bf16*)alloc((size_t)L_ * 2048 * 512 * 2);
  bf16* sfw2T  = (bf16*)alloc((size_t)L_ * 512 * 2048 * 2);
  bf16* xn    = (bf16*)alloc((size_t)4096 * 512 * 2);
  bf16* reg1  = (bf16*)alloc((size_t)12288 * 512 * 2);
  bf16* qb    = (bf16*)alloc((size_t)4096 * 512 * 2);
  bf16* reg2  = (bf16*)alloc((size_t)B_ * 4096 * 1024 * 2);
  bf16* vtb   = (bf16*)alloc((size_t)B_ * H_ * 64 * 4096 * 2);
  bf16* attnb = (bf16*)alloc((size_t)4096 * 512 * 2);
  // KV-split partials (guarded by ws_size)
  constexpr int NSPL = 4;
  constexpr int TOTR = B_ * H_ * QN;
  bf16* po = (bf16*)alloc((size_t)NSPL * TOTR * 64 * 2);
  float* pmb = (float*)alloc((size_t)NSPL * TOTR * 4);
  float* plb = (float*)alloc((size_t)NSPL * TOTR * 4);
  const bool use_split = (off <= ws_size);
  bf16* cn = reg1;
  bf16* qkvb = reg1;
  bf16* kvb = reg2;
  bf16* ffh = reg2;
  (void)in_sizes; (void)n_in; (void)out_size;

  // ---- batched weight prep (one dispatch) ----
  WPack wp;
  int nt_acc = 0, wi = 0;
  auto addw = [&](const float* s, bf16* d, int K, int N) {
    wp.d[wi].src = s; wp.d[wi].dst = d; wp.d[wi].K = K; wp.d[wi].N = N;
    wp.d[wi].tstart = nt_acc;
    nt_acc += (N / 64) * (K / 64);
    wi++;
  };
  addw(pa_wq, wqT, 512, 512);
  addw(pa_wkv, wkvT, 512, 1024);
  addw(pa_wo, woT, 512, 512);
  addw(pf_w1, w1T, 512, 2048);
  addw(pf_w2, w2T, 2048, 512);
  for (int l = 0; l < L_; l++) {
    addw(sa_wqkv + (size_t)l * 512 * 1536, saqkvT + (size_t)l * 1536 * 512, 512, 1536);
    addw(sa_wo + (size_t)l * 512 * 512, sawoT + (size_t)l * 512 * 512, 512, 512);
    addw(sf_w1 + (size_t)l * 512 * 2048, sfw1T + (size_t)l * 2048 * 512, 512, 2048);
    addw(sf_w2 + (size_t)l * 2048 * 512, sfw2T + (size_t)l * 512 * 2048, 2048, 512);
  }
  wp.n = wi;
  wtrans_all<<<nt_acc, dim3(64, 4, 1), 0, stream>>>(wp);

  // ---- prefix attention block ----
  ln_kernel<<<1024, 256, 0, stream>>>(x, pa_ng, pa_nb, xn, 4096);
  ln_kernel<<<3072, 256, 0, stream>>>(ctx, pa_cg, pa_cb, cn, 12288);
  launch_gemm(stream, 0, xn, wqT, qb, nullptr, nullptr, 4096, 512, 512, 4096, 4096, 0);
  launch_gemm(stream, 0, cn, wkvT, kvb, nullptr, nullptr, 12288, 1024, 512, 3072, 4096, 0);
  launch_gemm(stream, 0, xn, wkvT, kvb, nullptr, nullptr, 4096, 1024, 512, 1024, 4096, 3072);
  vtrans_kernel<<<dim3(64, H_, B_), dim3(64, 4, 1), 0, stream>>>(kvb, vtb, 4096, 1024, 512);
  if (use_split) {
    hipLaunchKernelGGL(HIP_KERNEL_NAME(attn_kernel<NSPL>), dim3((QN / 64) * NSPL, H_, B_), dim3(256), 0,
                       stream, qb, 512, kvb, 1024, vtb, attnb, po, pmb, plb, 4096, MCTX, 1024);
    hipLaunchKernelGGL(HIP_KERNEL_NAME(attn_combine<NSPL>), dim3(TOTR / 4), dim3(256), 0,
                       stream, po, pmb, plb, attnb);
  } else {
    hipLaunchKernelGGL(HIP_KERNEL_NAME(attn_kernel<1>), dim3(QN / 64, H_, B_), dim3(256), 0,
                       stream, qb, 512, kvb, 1024, vtb, attnb, po, pmb, plb, 4096, MCTX, 4096);
  }
  launch_gemm(stream, 2, attnb, woT, xo, x, pa_wob, 4096, 512, 512, 4096, 4096, 0);
  ln_kernel<<<1024, 256, 0, stream>>>(xo, pf_g, pf_b, xn, 4096);
  launch_gemm(stream, 1, xn, w1T, ffh, nullptr, nullptr, 4096, 2048, 512, 4096, 4096, 0);
  launch_gemm(stream, 2, ffh, w2T, xo, xo, nullptr, 4096, 512, 2048, 4096, 4096, 0);

  // ---- depth x (self-attn + FF) ----
  for (int l = 0; l < L_; l++) {
    ln_kernel<<<1024, 256, 0, stream>>>(xo, sa_g + l * 512, sa_b + l * 512, xn, 4096);
    launch_gemm(stream, 0, xn, saqkvT + (size_t)l * 1536 * 512, qkvb, nullptr, nullptr,
                4096, 1536, 512, 4096, 4096, 0);
    vtrans_kernel<<<dim3(16, H_, B_), dim3(64, 4, 1), 0, stream>>>(qkvb, vtb, 1024, 1536, 1024);
    hipLaunchKernelGGL(HIP_KERNEL_NAME(attn_kernel<1>), dim3(QN / 64, H_, B_), dim3(256), 0,
                       stream, qkvb, 1536, qkvb + 512, 1536, vtb, attnb, po, pmb, plb, 1024, 0, 1024);
    launch_gemm(stream, 2, attnb, sawoT + (size_t)l * 512 * 512, xo, xo, nullptr,
                4096, 512, 512, 4096, 4096, 0);
    ln_kernel<<<1024, 256, 0, stream>>>(xo, sf_g + l * 512, sf_b + l * 512, xn, 4096);
    launch_gemm(stream, 1, xn, sfw1T + (size_t)l * 2048 * 512, ffh, nullptr, nullptr,
                4096, 2048, 512, 4096, 4096, 0);
    launch_gemm(stream, 2, ffh, sfw2T + (size_t)l * 512 * 2048, xo, xo, nullptr,
                4096, 512, 2048, 4096, 4096, 0);
  }
}

// Round 5
// 910.780 us; speedup vs baseline: 1.8619x; 1.0587x over previous
//
#include <hip/hip_runtime.h>
#include <hip/hip_bf16.h>
#include <cstdint>
#include <cstddef>

typedef __bf16 bf16;
typedef __attribute__((ext_vector_type(8))) __bf16 bf16x8;
typedef __attribute__((ext_vector_type(4))) __bf16 bf16x4;
typedef __attribute__((ext_vector_type(4))) float f32x4;

constexpr int B_ = 4, QN = 1024, MCTX = 3072, D_ = 512, H_ = 8, DHE = 64, L_ = 6, FF_ = 2048;
constexpr float SCALE_ = 0.125f;  // 64^-0.5

__device__ __forceinline__ f32x4 mfma16(bf16x8 a, bf16x8 b, f32x4 c) {
  return __builtin_amdgcn_mfma_f32_16x16x32_bf16(a, b, c, 0, 0, 0);
}

__device__ __forceinline__ void gl_lds16(const bf16* g, bf16* l) {
  __builtin_amdgcn_global_load_lds((const __attribute__((address_space(1))) void*)g,
                                   (__attribute__((address_space(3))) void*)l, 16, 0, 0);
}

// ---------------- LayerNorm: fp32 in -> bf16 out, one wave per row (D=512) ----
__global__ __launch_bounds__(256) void ln_kernel(const float* __restrict__ x,
                                                 const float* __restrict__ g,
                                                 const float* __restrict__ b,
                                                 bf16* __restrict__ out, int rows) {
  int wid = threadIdx.x >> 6, lane = threadIdx.x & 63;
  int row = blockIdx.x * 4 + wid;
  if (row >= rows) return;
  const float* xr = x + (size_t)row * D_;
  f32x4 a0 = *(const f32x4*)(xr + lane * 8);
  f32x4 a1 = *(const f32x4*)(xr + lane * 8 + 4);
  float s = 0.f;
#pragma unroll
  for (int i = 0; i < 4; i++) { s += a0[i]; s += a1[i]; }
#pragma unroll
  for (int d = 1; d < 64; d <<= 1) s += __shfl_xor(s, d);
  float mean = s * (1.0f / 512.0f);
  float q = 0.f;
#pragma unroll
  for (int i = 0; i < 4; i++) {
    float t0 = a0[i] - mean, t1 = a1[i] - mean;
    q += t0 * t0 + t1 * t1;
  }
#pragma unroll
  for (int d = 1; d < 64; d <<= 1) q += __shfl_xor(q, d);
  float rstd = rsqrtf(q * (1.0f / 512.0f) + 1e-5f);
  f32x4 g0 = *(const f32x4*)(g + lane * 8);
  f32x4 g1 = *(const f32x4*)(g + lane * 8 + 4);
  f32x4 b0 = *(const f32x4*)(b + lane * 8);
  f32x4 b1 = *(const f32x4*)(b + lane * 8 + 4);
  bf16x8 o;
#pragma unroll
  for (int i = 0; i < 4; i++) {
    o[i] = (bf16)((a0[i] - mean) * rstd * g0[i] + b0[i]);
    o[i + 4] = (bf16)((a1[i] - mean) * rstd * g1[i] + b1[i]);
  }
  *(bf16x8*)(out + (size_t)row * D_ + lane * 8) = o;
}

// ------------- batched weight transpose fp32 [K][N] -> bf16 [N][K] ------------
struct WDesc { const float* src; bf16* dst; int K; int N; int tstart; };
struct WPack { WDesc d[30]; int n; };

__global__ __launch_bounds__(256) void wtrans_all(WPack p) {
  __shared__ float tile[64][65];
  const int bid = blockIdx.x;
  int mi = 0;
  for (int i = 1; i < p.n; i++)
    if (p.d[i].tstart <= bid) mi = i;
  const float* src = p.d[mi].src;
  bf16* dst = p.d[mi].dst;
  const int K = p.d[mi].K, N = p.d[mi].N;
  const int lt = bid - p.d[mi].tstart;
  const int ntx = N >> 6;
  const int n0 = (lt % ntx) * 64, k0 = (lt / ntx) * 64;
  const int tx = threadIdx.x, ty = threadIdx.y;
#pragma unroll
  for (int pp = 0; pp < 16; pp++)
    tile[pp * 4 + ty][tx] = src[(size_t)(k0 + pp * 4 + ty) * N + n0 + tx];
  __syncthreads();
#pragma unroll
  for (int pp = 0; pp < 16; pp++)
    dst[(size_t)(n0 + pp * 4 + ty) * K + k0 + tx] = (bf16)tile[tx][pp * 4 + ty];
}

// ------------- V repack: [b,s,stride] (col off) -> VT [b,h,dh,Skv], bf16 ------
__global__ __launch_bounds__(256) void vtrans_kernel(const bf16* __restrict__ src,
                                                     bf16* __restrict__ vt,
                                                     int Skv, int rstride, int coloff) {
  __shared__ bf16 tile[64][65];
  int tx = threadIdx.x, ty = threadIdx.y;
  int s0 = blockIdx.x * 64, h = blockIdx.y, b = blockIdx.z;
  const bf16* sp = src + (size_t)b * Skv * rstride + coloff + h * 64;
#pragma unroll
  for (int p = 0; p < 16; p++)
    tile[p * 4 + ty][tx] = sp[(size_t)(s0 + p * 4 + ty) * rstride + tx];
  __syncthreads();
  bf16* op = vt + ((size_t)(b * H_ + h) * 64) * Skv;
#pragma unroll
  for (int p = 0; p < 16; p++)
    op[(size_t)(p * 4 + ty) * Skv + s0 + tx] = tile[tx][p * 4 + ty];
}

// ------------- GEMM 128x128 tile, BK=64, 2-buf counted pipeline, swizzled -----
// Stage: wave w covers rows w*32+j*8 (j=0..3); lane l -> row +(l>>3),
// k-slot at lds slot (l&7) == global slot ((l&7) ^ (l>>3)).
// Read: row r, slot t=kk*4+lg -> lds slot t ^ (r&7).
template <int EPI>
__global__ __launch_bounds__(256) void gemm128(const bf16* __restrict__ A,
                                               const bf16* __restrict__ BT,
                                               void* __restrict__ Cout,
                                               const float* __restrict__ resid,
                                               const float* __restrict__ bias,
                                               int M, int N, int K,
                                               int rpbi, int rpbo, int roff) {
  __shared__ bf16 smA[2][128 * 64];
  __shared__ bf16 smB[2][128 * 64];
  const int tid = threadIdx.x, wid = tid >> 6, lane = tid & 63;
  const int lr = lane & 15, lg = lane >> 4;
  const int tm = blockIdx.y * 128, tn = blockIdx.x * 128;
  const int wr = (wid >> 1) * 64, wc = (wid & 1) * 64;

  const int l3 = lane >> 3;
  const int kslot = ((lane & 7) ^ l3) * 8;
  const bf16* gA[4];
  const bf16* gB[4];
#pragma unroll
  for (int j = 0; j < 4; j++) {
    gA[j] = A + (size_t)(tm + wid * 32 + j * 8 + l3) * K + kslot;
    gB[j] = BT + (size_t)(tn + wid * 32 + j * 8 + l3) * K + kslot;
  }

  f32x4 acc[4][4] = {};
  const int nt = K >> 6;

  auto stage = [&](int bi, int kt) {
#pragma unroll
    for (int j = 0; j < 4; j++) {
      gl_lds16(gA[j] + kt, &smA[bi][(wid * 32 + j * 8) * 64]);
      gl_lds16(gB[j] + kt, &smB[bi][(wid * 32 + j * 8) * 64]);
    }
  };

  stage(0, 0);
  int buf = 0;
  for (int t = 0; t < nt; ++t) {
    asm volatile("s_waitcnt vmcnt(0)" ::: "memory");
    __builtin_amdgcn_s_barrier();
    __builtin_amdgcn_sched_barrier(0);
    if (t + 1 < nt) stage(buf ^ 1, (t + 1) * 64);

    bf16x8 af[4][2], bfr[4][2];
#pragma unroll
    for (int i = 0; i < 4; i++) {
      const int row = wr + i * 16 + lr;
#pragma unroll
      for (int kk = 0; kk < 2; kk++)
        af[i][kk] = *(const bf16x8*)(&smA[buf][row * 64 + (((kk * 4 + lg) ^ (row & 7)) * 8)]);
    }
#pragma unroll
    for (int j = 0; j < 4; j++) {
      const int row = wc + j * 16 + lr;
#pragma unroll
      for (int kk = 0; kk < 2; kk++)
        bfr[j][kk] = *(const bf16x8*)(&smB[buf][row * 64 + (((kk * 4 + lg) ^ (row & 7)) * 8)]);
    }
#pragma unroll
    for (int kk = 0; kk < 2; kk++)
#pragma unroll
      for (int i = 0; i < 4; i++)
#pragma unroll
        for (int j = 0; j < 4; j++)
          acc[i][j] = mfma16(af[i][kk], bfr[j][kk], acc[i][j]);
    buf ^= 1;
  }

#pragma unroll
  for (int i = 0; i < 4; i++) {
#pragma unroll
    for (int r = 0; r < 4; r++) {
      int row = tm + wr + i * 16 + lg * 4 + r;
      int orow = (row / rpbi) * rpbo + (row % rpbi) + roff;
#pragma unroll
      for (int j = 0; j < 4; j++) {
        int col = tn + wc + j * 16 + lr;
        float v = acc[i][j][r];
        if (EPI == 0) {
          ((bf16*)Cout)[(size_t)orow * N + col] = (bf16)v;
        } else if (EPI == 1) {
          float gv = 0.5f * v * (1.0f + erff(v * 0.70710678118f));
          ((bf16*)Cout)[(size_t)orow * N + col] = (bf16)gv;
        } else {
          if (bias) v += bias[col];
          v += resid[(size_t)orow * N + col];
          ((float*)Cout)[(size_t)orow * N + col] = v;
        }
      }
    }
  }
}

// ------------- GEMM 64x64 tile, BK=64, 3-stage counted-vmcnt pipeline ---------
template <int EPI>
__global__ __launch_bounds__(256) void gemm64(const bf16* __restrict__ A,
                                              const bf16* __restrict__ BT,
                                              void* __restrict__ Cout,
                                              const float* __restrict__ resid,
                                              const float* __restrict__ bias,
                                              int M, int N, int K,
                                              int rpbi, int rpbo, int roff) {
  __shared__ bf16 smA[3][64 * 64];
  __shared__ bf16 smB[3][64 * 64];
  const int tid = threadIdx.x, wid = tid >> 6, lane = tid & 63;
  const int lr = lane & 15, lg = lane >> 4;
  const int tm = blockIdx.y * 64, tn = blockIdx.x * 64;
  const int wr = (wid >> 1) * 32, wc = (wid & 1) * 32;

  const int l3 = lane >> 3;
  const int kslot = ((lane & 7) ^ l3) * 8;
  const int row0 = 2 * wid * 8 + l3;
  const bf16* gA0 = A + (size_t)(tm + row0) * K + kslot;
  const bf16* gA1 = A + (size_t)(tm + row0 + 8) * K + kslot;
  const bf16* gB0 = BT + (size_t)(tn + row0) * K + kslot;
  const bf16* gB1 = BT + (size_t)(tn + row0 + 8) * K + kslot;

  f32x4 acc[2][2] = {};
  const int nt = K >> 6;

  auto stage = [&](int bi, int kt) {
    gl_lds16(gA0 + kt, &smA[bi][(2 * wid) * 512]);
    gl_lds16(gA1 + kt, &smA[bi][(2 * wid + 1) * 512]);
    gl_lds16(gB0 + kt, &smB[bi][(2 * wid) * 512]);
    gl_lds16(gB1 + kt, &smB[bi][(2 * wid + 1) * 512]);
  };

  stage(0, 0);
  if (nt > 1) stage(1, 64);

  for (int t = 0; t < nt; ++t) {
    const int bi = t % 3;
    if (t + 1 < nt) {
      asm volatile("s_waitcnt vmcnt(4)" ::: "memory");
    } else {
      asm volatile("s_waitcnt vmcnt(0)" ::: "memory");
    }
    __builtin_amdgcn_s_barrier();
    __builtin_amdgcn_sched_barrier(0);
    if (t + 2 < nt) stage((t + 2) % 3, (t + 2) * 64);

    bf16x8 af[2][2], bfr[2][2];
#pragma unroll
    for (int i = 0; i < 2; i++) {
      const int row = wr + i * 16 + lr;
#pragma unroll
      for (int kk = 0; kk < 2; kk++)
        af[i][kk] = *(const bf16x8*)(&smA[bi][row * 64 + (((kk * 4 + lg) ^ (row & 7)) * 8)]);
    }
#pragma unroll
    for (int j = 0; j < 2; j++) {
      const int row = wc + j * 16 + lr;
#pragma unroll
      for (int kk = 0; kk < 2; kk++)
        bfr[j][kk] = *(const bf16x8*)(&smB[bi][row * 64 + (((kk * 4 + lg) ^ (row & 7)) * 8)]);
    }
#pragma unroll
    for (int kk = 0; kk < 2; kk++)
#pragma unroll
      for (int i = 0; i < 2; i++)
#pragma unroll
        for (int j = 0; j < 2; j++)
          acc[i][j] = mfma16(af[i][kk], bfr[j][kk], acc[i][j]);
  }

#pragma unroll
  for (int i = 0; i < 2; i++) {
#pragma unroll
    for (int r = 0; r < 4; r++) {
      int row = tm + wr + i * 16 + lg * 4 + r;
      int orow = (row / rpbi) * rpbo + (row % rpbi) + roff;
#pragma unroll
      for (int j = 0; j < 2; j++) {
        int col = tn + wc + j * 16 + lr;
        float v = acc[i][j][r];
        if (EPI == 0) {
          ((bf16*)Cout)[(size_t)orow * N + col] = (bf16)v;
        } else if (EPI == 1) {
          float gv = 0.5f * v * (1.0f + erff(v * 0.70710678118f));
          ((bf16*)Cout)[(size_t)orow * N + col] = (bf16)gv;
        } else {
          if (bias) v += bias[col];
          v += resid[(size_t)orow * N + col];
          ((float*)Cout)[(size_t)orow * N + col] = v;
        }
      }
    }
  }
}

// ------------- flash attention: swapped QK^T, 64-key LDS tiles, KV-split ------
template <int NSPLIT>
__global__ __launch_bounds__(256) void attn_kernel(const bf16* __restrict__ q, int qstride,
                                                   const bf16* __restrict__ k, int kstride,
                                                   const bf16* __restrict__ vt,
                                                   bf16* __restrict__ out,
                                                   bf16* __restrict__ po,
                                                   float* __restrict__ pm,
                                                   float* __restrict__ pl,
                                                   int Skv, int Moff, int spllen) {
  __shared__ bf16 kls[2][4096];
  __shared__ bf16 vls[2][4096];
  __shared__ bf16 pls[4][1024];

  const int tid = threadIdx.x, wid = tid >> 6, lane = tid & 63;
  const int lr = lane & 15, lg = lane >> 4, lg4 = lg * 4;
  const int b = blockIdx.z, h = blockIdx.y;
  const int qblk = blockIdx.x / NSPLIT;
  const int split = blockIdx.x % NSPLIT;
  const int q0b = qblk * 64;
  const int q0w = q0b + wid * 16;
  const int kv_lo = split * spllen;

  int jhi_blk = Moff + q0b + 63;
  if (jhi_blk > Skv - 1) jhi_blk = Skv - 1;
  int hi = kv_lo + spllen;
  if (hi > jhi_blk + 1) hi = jhi_blk + 1;
  const int ntl = (hi > kv_lo) ? ((hi - kv_lo + 63) >> 6) : 0;

  if (NSPLIT > 1 && ntl == 0) {
    size_t rb = ((size_t)split * B_ * H_ + (size_t)b * H_ + h) * QN + q0w;
#pragma unroll
    for (int f = 0; f < 4; f++)
#pragma unroll
      for (int r = 0; r < 4; r++) po[(rb + lg4 + r) * 64 + f * 16 + lr] = (bf16)0.f;
    if (lg == 0) { pm[rb + lr] = -3e38f; pl[rb + lr] = 0.f; }
    return;
  }

  const int ss = (tid >> 6) & 1;
  const int sel = ss * 32 + ((tid >> 4) & 3) * 8;
  const int srow0 = (tid >> 7) * 16 + (tid & 15);
  const bf16* kbase = k + (size_t)b * Skv * kstride + h * DHE + sel;
  const bf16* vbase = vt + (size_t)((b * H_ + h) * DHE) * Skv + sel;

  const bf16* qp = q + (size_t)(b * QN + q0w + lr) * qstride + h * DHE;
  bf16x8 qa0 = *(const bf16x8*)(qp + lg * 8);
  bf16x8 qa1 = *(const bf16x8*)(qp + 32 + lg * 8);
#pragma unroll
  for (int i = 0; i < 8; i++) {
    qa0[i] = (bf16)((float)qa0[i] * SCALE_);
    qa1[i] = (bf16)((float)qa1[i] * SCALE_);
  }

  f32x4 o[4] = {};
  float mr = -3e38f, lrun = 0.f;

  auto stage = [&](int bi, int j0) {
    gl_lds16(kbase + (size_t)(j0 + srow0) * kstride, &kls[bi][wid * 512]);
    gl_lds16(kbase + (size_t)(j0 + srow0 + 32) * kstride, &kls[bi][2048 + wid * 512]);
    gl_lds16(vbase + (size_t)srow0 * Skv + j0, &vls[bi][wid * 512]);
    gl_lds16(vbase + (size_t)(srow0 + 32) * Skv + j0, &vls[bi][2048 + wid * 512]);
  };

  stage(0, kv_lo);
  __syncthreads();
  int buf = 0;
  bf16* pw = &pls[wid][0];

  for (int t = 0; t < ntl; ++t) {
    const int j0 = kv_lo + t * 64;
    if (t + 1 < ntl) stage(buf ^ 1, j0 + 64);
    const bf16* kbp = &kls[buf][0];
    const bf16* vbp = &vls[buf][0];

    f32x4 sv[4];
    __builtin_amdgcn_s_setprio(1);
#pragma unroll
    for (int kg = 0; kg < 4; kg++) {
      bf16x8 k0 = *(const bf16x8*)(kbp + (kg * 128 + lane) * 8);
      bf16x8 k1 = *(const bf16x8*)(kbp + (kg * 128 + 64 + lane) * 8);
      f32x4 z = {0.f, 0.f, 0.f, 0.f};
      z = mfma16(k0, qa0, z);
      z = mfma16(k1, qa1, z);
      sv[kg] = z;
    }
    __builtin_amdgcn_s_setprio(0);
    const bool full = (j0 + 63 <= Moff + q0w);
    if (!full) {
      const int limq = Moff + q0w + lr;
#pragma unroll
      for (int kg = 0; kg < 4; kg++)
#pragma unroll
        for (int r = 0; r < 4; r++)
          if (j0 + kg * 16 + lg4 + r > limq) sv[kg][r] = -3e38f;
    }
    float pmax = sv[0][0];
#pragma unroll
    for (int kg = 0; kg < 4; kg++)
#pragma unroll
      for (int r = 0; r < 4; r++) pmax = fmaxf(pmax, sv[kg][r]);
    pmax = fmaxf(pmax, __shfl_xor(pmax, 16));
    pmax = fmaxf(pmax, __shfl_xor(pmax, 32));
    if (__any(pmax > mr + 8.f)) {
      float mn = fmaxf(mr, pmax);
      float scl = __expf(mr - mn);
      mr = mn;
      lrun *= scl;
      float c0 = __shfl(scl, lg4 + 0), c1 = __shfl(scl, lg4 + 1);
      float c2 = __shfl(scl, lg4 + 2), c3 = __shfl(scl, lg4 + 3);
#pragma unroll
      for (int f = 0; f < 4; f++) {
        o[f][0] *= c0; o[f][1] *= c1; o[f][2] *= c2; o[f][3] *= c3;
      }
    }
    float rsum = 0.f;
#pragma unroll
    for (int kg = 0; kg < 4; kg++) {
      float p0 = __expf(sv[kg][0] - mr);
      float p1 = __expf(sv[kg][1] - mr);
      float p2 = __expf(sv[kg][2] - mr);
      float p3 = __expf(sv[kg][3] - mr);
      rsum += (p0 + p1) + (p2 + p3);
      bf16x4 pk = {(bf16)p0, (bf16)p1, (bf16)p2, (bf16)p3};
      const int k8 = kg * 2 + (lg >> 1);
      *(bf16x4*)(pw + ((k8 >> 2) * 64 + (k8 & 3) * 16 + lr) * 8 + (lg & 1) * 4) = pk;
    }
    rsum += __shfl_xor(rsum, 16);
    rsum += __shfl_xor(rsum, 32);
    lrun += rsum;
    bf16x8 pa0 = *(const bf16x8*)(pw + lane * 8);
    bf16x8 pa1 = *(const bf16x8*)(pw + (64 + lane) * 8);
    __builtin_amdgcn_s_setprio(1);
#pragma unroll
    for (int f = 0; f < 4; f++) {
      bf16x8 v0 = *(const bf16x8*)(vbp + (f * 128 + lane) * 8);
      bf16x8 v1 = *(const bf16x8*)(vbp + (f * 128 + 64 + lane) * 8);
      o[f] = mfma16(pa0, v0, o[f]);
      o[f] = mfma16(pa1, v1, o[f]);
    }
    __builtin_amdgcn_s_setprio(0);
    __syncthreads();
    buf ^= 1;
  }

  if (NSPLIT == 1) {
    float linv = 1.0f / lrun;
    float li[4];
#pragma unroll
    for (int r = 0; r < 4; r++) li[r] = __shfl(linv, lg4 + r);
#pragma unroll
    for (int f = 0; f < 4; f++)
#pragma unroll
      for (int r = 0; r < 4; r++)
        out[(size_t)(b * QN + q0w + lg4 + r) * D_ + h * DHE + f * 16 + lr] =
            (bf16)(o[f][r] * li[r]);
  } else {
    size_t rb = ((size_t)split * B_ * H_ + (size_t)b * H_ + h) * QN + q0w;
#pragma unroll
    for (int f = 0; f < 4; f++)
#pragma unroll
      for (int r = 0; r < 4; r++)
        po[(rb + lg4 + r) * 64 + f * 16 + lr] = (bf16)o[f][r];
    if (lg == 0) { pm[rb + lr] = mr; pl[rb + lr] = lrun; }
  }
}

// ------------- combine: merge NSPLIT partial (O,m,l) -> bf16 out --------------
template <int NSPLIT>
__global__ __launch_bounds__(256) void attn_combine(const bf16* __restrict__ po,
                                                    const float* __restrict__ pm,
                                                    const float* __restrict__ pl,
                                                    bf16* __restrict__ out) {
  constexpr int TOT = B_ * H_ * QN;
  const int wid = threadIdx.x >> 6, lane = threadIdx.x & 63;
  const int row = blockIdx.x * 4 + wid;  // (b*H+h)*QN + q
  float mv[NSPLIT], lv[NSPLIT];
  float mstar = -3e38f;
#pragma unroll
  for (int s = 0; s < NSPLIT; s++) {
    mv[s] = pm[s * TOT + row];
    lv[s] = pl[s * TOT + row];
    mstar = fmaxf(mstar, mv[s]);
  }
  float lstar = 0.f, acc = 0.f;
#pragma unroll
  for (int s = 0; s < NSPLIT; s++) {
    float w = __expf(mv[s] - mstar);
    lstar += lv[s] * w;
    acc += (float)po[((size_t)s * TOT + row) * 64 + lane] * w;
  }
  const int b = row >> 13, hq = row & 8191, h = hq >> 10, qq = hq & 1023;
  out[((size_t)b * QN + qq) * D_ + h * DHE + lane] = (bf16)(acc / lstar);
}

// -----------------------------------------------------------------------------
static void launch_gemm(hipStream_t st, int epi, const bf16* A, const bf16* BT, void* C,
                        const float* res, const float* bias,
                        int M, int N, int K, int rpbi, int rpbo, int roff) {
  if (N >= 1024) {
    dim3 grid(N / 128, M / 128), blk(256, 1, 1);
    switch (epi) {
      case 0:
        hipLaunchKernelGGL(HIP_KERNEL_NAME(gemm128<0>), grid, blk, 0, st, A, BT, C, res, bias, M, N, K, rpbi, rpbo, roff);
        break;
      case 1:
        hipLaunchKernelGGL(HIP_KERNEL_NAME(gemm128<1>), grid, blk, 0, st, A, BT, C, res, bias, M, N, K, rpbi, rpbo, roff);
        break;
      default:
        hipLaunchKernelGGL(HIP_KERNEL_NAME(gemm128<2>), grid, blk, 0, st, A, BT, C, res, bias, M, N, K, rpbi, rpbo, roff);
        break;
    }
    return;
  }
  dim3 grid(N / 64, M / 64), blk(256, 1, 1);
  switch (epi) {
    case 0:
      hipLaunchKernelGGL(HIP_KERNEL_NAME(gemm64<0>), grid, blk, 0, st, A, BT, C, res, bias, M, N, K, rpbi, rpbo, roff);
      break;
    case 1:
      hipLaunchKernelGGL(HIP_KERNEL_NAME(gemm64<1>), grid, blk, 0, st, A, BT, C, res, bias, M, N, K, rpbi, rpbo, roff);
      break;
    default:
      hipLaunchKernelGGL(HIP_KERNEL_NAME(gemm64<2>), grid, blk, 0, st, A, BT, C, res, bias, M, N, K, rpbi, rpbo, roff);
      break;
  }
}

extern "C" void kernel_launch(void* const* d_in, const int* in_sizes, int n_in,
                              void* d_out, int out_size, void* d_ws, size_t ws_size,
                              hipStream_t stream) {
  const float* x       = (const float*)d_in[0];
  const float* ctx     = (const float*)d_in[1];
  const float* pa_ng   = (const float*)d_in[2];
  const float* pa_nb   = (const float*)d_in[3];
  const float* pa_cg   = (const float*)d_in[4];
  const float* pa_cb   = (const float*)d_in[5];
  const float* pa_wq   = (const float*)d_in[6];
  const float* pa_wkv  = (const float*)d_in[7];
  const float* pa_wo   = (const float*)d_in[8];
  const float* pa_wob  = (const float*)d_in[9];
  const float* pf_g    = (const float*)d_in[10];
  const float* pf_b    = (const float*)d_in[11];
  const float* pf_w1   = (const float*)d_in[12];
  const float* pf_w2   = (const float*)d_in[13];
  const float* sa_g    = (const float*)d_in[14];
  const float* sa_b    = (const float*)d_in[15];
  const float* sa_wqkv = (const float*)d_in[16];
  const float* sa_wo   = (const float*)d_in[17];
  const float* sf_g    = (const float*)d_in[18];
  const float* sf_b    = (const float*)d_in[19];
  const float* sf_w1   = (const float*)d_in[20];
  const float* sf_w2   = (const float*)d_in[21];
  float* xo = (float*)d_out;

  char* ws = (char*)d_ws;
  size_t off = 0;
  auto alloc = [&](size_t bytes) -> char* {
    char* p = ws + off;
    off += (bytes + 255) & ~(size_t)255;
    return p;
  };

  bf16* wqT    = (bf16*)alloc((size_t)512 * 512 * 2);
  bf16* wkvT   = (bf16*)alloc((size_t)1024 * 512 * 2);
  bf16* woT    = (bf16*)alloc((size_t)512 * 512 * 2);
  bf16* w1T    = (bf16*)alloc((size_t)2048 * 512 * 2);
  bf16* w2T    = (bf16*)alloc((size_t)512 * 2048 * 2);
  bf16* saqkvT = (bf16*)alloc((size_t)L_ * 1536 * 512 * 2);
  bf16* sawoT  = (bf16*)alloc((size_t)L_ * 512 * 512 * 2);
  bf16* sfw1T  = (bf16*)alloc((size_t)L_ * 2048 * 512 * 2);
  bf16* sfw2T  = (bf16*)alloc((size_t)L_ * 512 * 2048 * 2);
  bf16* xn    = (bf16*)alloc((size_t)4096 * 512 * 2);
  bf16* reg1  = (bf16*)alloc((size_t)12288 * 512 * 2);
  bf16* qb    = (bf16*)alloc((size_t)4096 * 512 * 2);
  bf16* reg2  = (bf16*)alloc((size_t)B_ * 4096 * 1024 * 2);
  bf16* vtb   = (bf16*)alloc((size_t)B_ * H_ * 64 * 4096 * 2);
  bf16* attnb = (bf16*)alloc((size_t)4096 * 512 * 2);
  constexpr int NSPL = 4;
  constexpr int TOTR = B_ * H_ * QN;
  bf16* po = (bf16*)alloc((size_t)NSPL * TOTR * 64 * 2);
  float* pmb = (float*)alloc((size_t)NSPL * TOTR * 4);
  float* plb = (float*)alloc((size_t)NSPL * TOTR * 4);
  const bool use_split = (off <= ws_size);
  bf16* cn = reg1;
  bf16* qkvb = reg1;
  bf16* kvb = reg2;
  bf16* ffh = reg2;
  (void)in_sizes; (void)n_in; (void)out_size;

  // ---- batched weight prep (one dispatch) ----
  WPack wp;
  int nt_acc = 0, wi = 0;
  auto addw = [&](const float* s, bf16* d, int K, int N) {
    wp.d[wi].src = s; wp.d[wi].dst = d; wp.d[wi].K = K; wp.d[wi].N = N;
    wp.d[wi].tstart = nt_acc;
    nt_acc += (N / 64) * (K / 64);
    wi++;
  };
  addw(pa_wq, wqT, 512, 512);
  addw(pa_wkv, wkvT, 512, 1024);
  addw(pa_wo, woT, 512, 512);
  addw(pf_w1, w1T, 512, 2048);
  addw(pf_w2, w2T, 2048, 512);
  for (int l = 0; l < L_; l++) {
    addw(sa_wqkv + (size_t)l * 512 * 1536, saqkvT + (size_t)l * 1536 * 512, 512, 1536);
    addw(sa_wo + (size_t)l * 512 * 512, sawoT + (size_t)l * 512 * 512, 512, 512);
    addw(sf_w1 + (size_t)l * 512 * 2048, sfw1T + (size_t)l * 2048 * 512, 512, 2048);
    addw(sf_w2 + (size_t)l * 2048 * 512, sfw2T + (size_t)l * 512 * 2048, 2048, 512);
  }
  wp.n = wi;
  wtrans_all<<<nt_acc, dim3(64, 4, 1), 0, stream>>>(wp);

  // ---- prefix attention block ----
  ln_kernel<<<1024, 256, 0, stream>>>(x, pa_ng, pa_nb, xn, 4096);
  ln_kernel<<<3072, 256, 0, stream>>>(ctx, pa_cg, pa_cb, cn, 12288);
  launch_gemm(stream, 0, xn, wqT, qb, nullptr, nullptr, 4096, 512, 512, 4096, 4096, 0);
  launch_gemm(stream, 0, cn, wkvT, kvb, nullptr, nullptr, 12288, 1024, 512, 3072, 4096, 0);
  launch_gemm(stream, 0, xn, wkvT, kvb, nullptr, nullptr, 4096, 1024, 512, 1024, 4096, 3072);
  vtrans_kernel<<<dim3(64, H_, B_), dim3(64, 4, 1), 0, stream>>>(kvb, vtb, 4096, 1024, 512);
  if (use_split) {
    hipLaunchKernelGGL(HIP_KERNEL_NAME(attn_kernel<NSPL>), dim3((QN / 64) * NSPL, H_, B_), dim3(256), 0,
                       stream, qb, 512, kvb, 1024, vtb, attnb, po, pmb, plb, 4096, MCTX, 1024);
    hipLaunchKernelGGL(HIP_KERNEL_NAME(attn_combine<NSPL>), dim3(TOTR / 4), dim3(256), 0,
                       stream, po, pmb, plb, attnb);
  } else {
    hipLaunchKernelGGL(HIP_KERNEL_NAME(attn_kernel<1>), dim3(QN / 64, H_, B_), dim3(256), 0,
                       stream, qb, 512, kvb, 1024, vtb, attnb, po, pmb, plb, 4096, MCTX, 4096);
  }
  launch_gemm(stream, 2, attnb, woT, xo, x, pa_wob, 4096, 512, 512, 4096, 4096, 0);
  ln_kernel<<<1024, 256, 0, stream>>>(xo, pf_g, pf_b, xn, 4096);
  launch_gemm(stream, 1, xn, w1T, ffh, nullptr, nullptr, 4096, 2048, 512, 4096, 4096, 0);
  launch_gemm(stream, 2, ffh, w2T, xo, xo, nullptr, 4096, 512, 2048, 4096, 4096, 0);

  // ---- depth x (self-attn + FF) ----
  for (int l = 0; l < L_; l++) {
    ln_kernel<<<1024, 256, 0, stream>>>(xo, sa_g + l * 512, sa_b + l * 512, xn, 4096);
    launch_gemm(stream, 0, xn, saqkvT + (size_t)l * 1536 * 512, qkvb, nullptr, nullptr,
                4096, 1536, 512, 4096, 4096, 0);
    vtrans_kernel<<<dim3(16, H_, B_), dim3(64, 4, 1), 0, stream>>>(qkvb, vtb, 1024, 1536, 1024);
    if (use_split) {
      hipLaunchKernelGGL(HIP_KERNEL_NAME(attn_kernel<2>), dim3((QN / 64) * 2, H_, B_), dim3(256), 0,
                         stream, qkvb, 1536, qkvb + 512, 1536, vtb, attnb, po, pmb, plb, 1024, 0, 512);
      hipLaunchKernelGGL(HIP_KERNEL_NAME(attn_combine<2>), dim3(TOTR / 4), dim3(256), 0,
                         stream, po, pmb, plb, attnb);
    } else {
      hipLaunchKernelGGL(HIP_KERNEL_NAME(attn_kernel<1>), dim3(QN / 64, H_, B_), dim3(256), 0,
                         stream, qkvb, 1536, qkvb + 512, 1536, vtb, attnb, po, pmb, plb, 1024, 0, 1024);
    }
    launch_gemm(stream, 2, attnb, sawoT + (size_t)l * 512 * 512, xo, xo, nullptr,
                4096, 512, 512, 4096, 4096, 0);
    ln_kernel<<<1024, 256, 0, stream>>>(xo, sf_g + l * 512, sf_b + l * 512, xn, 4096);
    launch_gemm(stream, 1, xn, sfw1T + (size_t)l * 2048 * 512, ffh, nullptr, nullptr,
                4096, 2048, 512, 4096, 4096, 0);
    launch_gemm(stream, 2, ffh, sfw2T + (size_t)l * 512 * 2048, xo, xo, nullptr,
                4096, 512, 2048, 4096, 4096, 0);
  }
}